// Round 2
// baseline (2564.736 us; speedup 1.0000x reference)
//
#include <hip/hip_runtime.h>

// ---------------------------------------------------------------------------
// <psi|U^dag O U|psi>, NQ=8, r=64 d=16 rl=16 ro=4.
// R14 = R13 + register-occupancy fix on the three heavy GEMMs:
//   rocprof showed Occupancy 25% / MfmaUtil 21% on gemm_g45 (and the same
//   acc[4][4] structure in G1/G2): 80 arch VGPR + 80 acc regs = ~160 total
//   -> 2 waves/SIMD. Halve per-wave accumulators (acc[2][4], two mt-passes,
//   B operands re-read from L2) + __launch_bounds__(256,4) -> <=128 regs
//   -> 4 waves/SIMD. Same MFMA order => bit-identical results.
//   G1 also stages both K-tiles once (16.6KB LDS, single barrier).
// Everything else identical to R13 (c-pairing, env pre-split, f16
// intermediates + power-of-2 scaling, fp32 boundary chains).
// ---------------------------------------------------------------------------

typedef __attribute__((ext_vector_type(8))) short bf16x8;
typedef __attribute__((ext_vector_type(8))) _Float16 f16x8;
typedef __attribute__((ext_vector_type(4))) float f32x4;
typedef __attribute__((ext_vector_type(4))) unsigned short us4;
typedef __attribute__((ext_vector_type(2))) unsigned short us2;

static __device__ __forceinline__ unsigned short f2bf(float x) {
    union { float f; unsigned u; } a; a.f = x;
    return (unsigned short)((a.u + 0x7FFF + ((a.u >> 16) & 1)) >> 16);
}
static __device__ __forceinline__ float bf2f(unsigned short h) {
    union { unsigned u; float f; } a; a.u = (unsigned)h << 16; return a.f;
}
static __device__ __forceinline__ unsigned split2(float x) {
    unsigned short h = f2bf(x);
    unsigned short l = f2bf(x - bf2f(h));
    return (unsigned)h | ((unsigned)l << 16);
}
static __device__ __forceinline__ unsigned short f2h_bits(float x) {
    union { _Float16 h; unsigned short u; } c; c.h = (_Float16)x; return c.u;
}
static __device__ __forceinline__ float h2f_bits(unsigned short u) {
    union { unsigned short u; _Float16 h; } c; c.u = u; return (float)c.h;
}

__global__ void write_diag_kernel(float* out, float v) {
    if (threadIdx.x == 0 && blockIdx.x == 0) out[0] = v;
}
__global__ void zero_out(float* o) {
    if (threadIdx.x == 0 && blockIdx.x == 0) o[0] = 0.0f;
}

// ---- A-operand fragment packs -------------------------------------------
__global__ void prep_apack(const float* __restrict__ layer,
                           unsigned short* __restrict__ Ap2,
                           unsigned short* __restrict__ Ap4) {
    int idx = blockIdx.x * 256 + threadIdx.x;   // 65536
    int q = idx >> 13, k0 = (idx >> 10) & 7, mt = (idx >> 6) & 15, lane = idx & 63;
    int quad = lane >> 4, r = lane & 15;
    unsigned short h2[8], l2[8], h4[8], l4[8];
#pragma unroll
    for (int j = 0; j < 8; j++) {
        int k = k0 * 32 + quad * 8 + j;
        int m = mt * 16 + r;
        float v2 = layer[(size_t)q * 65536 +
                         (size_t)((((k >> 4) * 16 + (m >> 4)) * 16 + (k & 15)) * 16 + (m & 15))];
        float v4 = layer[(size_t)q * 65536 +
                         (size_t)((((k >> 4) * 16 + (k & 15)) * 16 + (m >> 4)) * 16 + (m & 15))];
        h2[j] = f2h_bits(v2); l2[j] = f2h_bits(v2 - h2f_bits(h2[j]));
        h4[j] = f2h_bits(v4); l4[j] = f2h_bits(v4 - h2f_bits(h4[j]));
    }
    size_t base = ((size_t)((q * 8 + k0) * 16 + mt) * 2) * 512 + lane * 8;
    *(us4*)(Ap2 + base)       = *(us4*)&h2[0];
    *(us4*)(Ap2 + base + 4)   = *(us4*)&h2[4];
    *(us4*)(Ap2 + base + 512) = *(us4*)&l2[0];
    *(us4*)(Ap2 + base + 516) = *(us4*)&l2[4];
    *(us4*)(Ap4 + base)       = *(us4*)&h4[0];
    *(us4*)(Ap4 + base + 4)   = *(us4*)&h4[4];
    *(us4*)(Ap4 + base + 512) = *(us4*)&l4[0];
    *(us4*)(Ap4 + base + 516) = *(us4*)&l4[4];
}

__global__ void prep_spack1(const float* __restrict__ state,
                            unsigned short* __restrict__ Sp1) {
    int idx = blockIdx.x * 256 + threadIdx.x;   // 65536
    int q = idx >> 13, c = (idx >> 11) & 3, k0 = (idx >> 10) & 1,
        mt = (idx >> 6) & 15, lane = idx & 63;
    int quad = lane >> 4, lr = lane & 15;
    unsigned short h[8], l[8];
#pragma unroll
    for (int j = 0; j < 8; j++) {
        int k = k0 * 32 + quad * 8 + j;
        float v = state[(size_t)q * 65536 + (size_t)(k * 16 + mt) * 64 + c * 16 + lr];
        h[j] = f2bf(v); l[j] = f2bf(v - bf2f(h[j]));
    }
    size_t base = (size_t)(q * 4 + c) * 32768 + ((size_t)(k0 * 16 + mt) * 2) * 512 + lane * 8;
    *(us4*)(Sp1 + base)       = *(us4*)&h[0];
    *(us4*)(Sp1 + base + 4)   = *(us4*)&h[4];
    *(us4*)(Sp1 + base + 512) = *(us4*)&l[0];
    *(us4*)(Sp1 + base + 516) = *(us4*)&l[4];
}

__global__ void prep_spack5(const float* __restrict__ state,
                            unsigned short* __restrict__ Sp5) {
    int idx = blockIdx.x * 256 + threadIdx.x;   // 65536
    int q = idx >> 13, k0 = (idx >> 8) & 31, mt = (idx >> 6) & 3, lane = idx & 63;
    int quad = lane >> 4, lr = lane & 15;
    unsigned short h[8], l[8];
#pragma unroll
    for (int j = 0; j < 8; j++) {
        int k = k0 * 32 + quad * 8 + j;   // k = s*64+b
        int s = k >> 6, b = k & 63;
        float v = state[(size_t)q * 65536 + (size_t)(b * 16 + s) * 64 + mt * 16 + lr];
        h[j] = f2bf(v); l[j] = f2bf(v - bf2f(h[j]));
    }
    size_t base = (size_t)q * 131072 + ((size_t)(k0 * 4 + mt) * 2) * 512 + lane * 8;
    *(us4*)(Sp5 + base)       = *(us4*)&h[0];
    *(us4*)(Sp5 + base + 4)   = *(us4*)&h[4];
    *(us4*)(Sp5 + base + 512) = *(us4*)&l[0];
    *(us4*)(Sp5 + base + 516) = *(us4*)&l[4];
}

__global__ void prep_opack3(const float* __restrict__ oper,
                            unsigned short* __restrict__ Op3) {
    int idx = blockIdx.x * 256 + threadIdx.x;   // 4096
    int q = idx >> 9, k0 = (idx >> 8) & 1, mt = (idx >> 6) & 3, lane = idx & 63;
    int quad = lane >> 4, lr = lane & 15;
    unsigned short h[8], l[8];
#pragma unroll
    for (int j = 0; j < 8; j++) {
        int k = k0 * 32 + quad * 8 + j;
        int m = mt * 16 + lr;
        float v = oper[(size_t)q * 4096 + (size_t)(k * 16 + (m & 15)) * 4 + (m >> 4)];
        h[j] = f2h_bits(v); l[j] = f2h_bits(v - h2f_bits(h[j]));
    }
    size_t base = (size_t)q * 8192 + ((size_t)(k0 * 4 + mt) * 2) * 512 + lane * 8;
    *(us4*)(Op3 + base)       = *(us4*)&h[0];
    *(us4*)(Op3 + base + 4)   = *(us4*)&h[4];
    *(us4*)(Op3 + base + 512) = *(us4*)&l[0];
    *(us4*)(Op3 + base + 516) = *(us4*)&l[4];
}

// ---- env fp32 -> packed u32 (bf16 hi | lo<<16), once per site -----------
__global__ void env_split_k(const float* __restrict__ env, unsigned* __restrict__ envS) {
    int t = blockIdx.x * 256 + threadIdx.x;   // 1048576 x float4
    float4 v = ((const float4*)env)[t];
    uint4 o;
    o.x = split2(v.x); o.y = split2(v.y); o.z = split2(v.z); o.w = split2(v.w);
    ((uint4*)envS)[t] = o;
}

// ---- site 0 (env0 = delta): env1 built by a cheap chain (fp32 exact) ----
__global__ void s0_g2(const float* __restrict__ state, const float* __restrict__ layer,
                      float* __restrict__ g2) {
    int t = blockIdx.x * 256 + threadIdx.x;          // 16384: [A][j][L]
    int A = t >> 8, j = (t >> 4) & 15, L = t & 15;
    float s = 0;
    for (int i = 0; i < 16; i++) s += state[i * 64 + A] * layer[(j * 16 + i) * 16 + L];
    g2[t] = s;
}
__global__ void s0_g3(const float* __restrict__ g2, const float* __restrict__ oper,
                      float* __restrict__ g3) {
    int t = blockIdx.x * 256 + threadIdx.x;          // 65536: [A][L][k][O]
    int A = t >> 10, L = (t >> 6) & 15, k = (t >> 2) & 15, O = t & 3;
    float s = 0;
    for (int j = 0; j < 16; j++) s += g2[A * 256 + j * 16 + L] * oper[(j * 16 + k) * 4 + O];
    g3[t] = s;
}
__global__ void s0_g4(const float* __restrict__ g3, const float* __restrict__ layer,
                      float* __restrict__ g4) {
    int t = blockIdx.x * 256 + threadIdx.x;          // 1048576: [A][L][O][s][M]
    int A = t >> 14, L = (t >> 10) & 15, O = (t >> 8) & 3, sp = (t >> 4) & 15, M = t & 15;
    float s = 0;
    for (int k = 0; k < 16; k++)
        s += g3[A * 1024 + L * 64 + k * 4 + O] * layer[(k * 16 + sp) * 16 + M];
    g4[t] = s;
}
__global__ void s0_env(const float* __restrict__ g4, const float* __restrict__ state,
                       float* __restrict__ env) {
    int t = blockIdx.x * 256 + threadIdx.x;          // 4194304
    int A = t >> 16, L = (t >> 12) & 15, O = (t >> 10) & 3, M = (t >> 6) & 15, B = t & 63;
    float s = 0;
    for (int sp = 0; sp < 16; sp++)
        s += g4[A * 16384 + L * 1024 + O * 256 + sp * 16 + M] * state[sp * 64 + B];
    env[(size_t)(L * 64 + O * 16 + M) * 4096 + A * 64 + B] = s;
}

// ---- site 7 chain (fp32) + fused dot ------------------------------------
__global__ void s7_c1(const float* __restrict__ state, const float* __restrict__ layer,
                      float* __restrict__ c1) {
    int t = blockIdx.x * 256 + threadIdx.x;          // 16384: [l][a][j]
    int l = t >> 10, a = (t >> 4) & 63, j = t & 15;
    float s = 0;
    for (int i = 0; i < 16; i++)
        s += state[7 * 65536 + (a * 16 + i) * 64] * layer[7 * 65536 + ((l * 16 + j) * 16 + i) * 16];
    c1[t] = s;
}
__global__ void s7_c2(const float* __restrict__ c1, const float* __restrict__ oper,
                      float* __restrict__ c2) {
    int t = blockIdx.x * 256 + threadIdx.x;          // 65536: [o][l][a][k]
    int o = t >> 14, l = (t >> 10) & 15, a = (t >> 4) & 63, k = t & 15;
    float s = 0;
    for (int j = 0; j < 16; j++)
        s += c1[l * 1024 + a * 16 + j] * oper[7 * 4096 + ((o * 16 + j) * 16 + k) * 4];
    c2[t] = s;
}
__global__ void s7_c3(const float* __restrict__ c2, const float* __restrict__ layer,
                      float* __restrict__ c3) {
    int t = blockIdx.x * 256 + threadIdx.x;          // 1048576: [m][o][l][a][s]
    int m = t >> 16, o = (t >> 14) & 3, l = (t >> 10) & 15, a = (t >> 4) & 63, sp = t & 15;
    float s = 0;
    for (int k = 0; k < 16; k++)
        s += c2[o * 16384 + l * 1024 + a * 16 + k] *
             layer[7 * 65536 + ((m * 16 + k) * 16 + sp) * 16];
    c3[t] = s;
}
__global__ void prep_sv(const float* __restrict__ state, float* __restrict__ sv) {
    int t = blockIdx.x * 256 + threadIdx.x;          // 1024: [b][sp]
    sv[t] = state[7 * 65536 + t * 64];
}
__global__ __launch_bounds__(256) void s7_fused(const float* __restrict__ env,
                                                const float* __restrict__ c3,
                                                const float* __restrict__ sv,
                                                float* __restrict__ out) {
    __shared__ float c3s[1024], svs[1024], red[256];
    int t = threadIdx.x;
    int n0 = blockIdx.x * 64;            // region=(l,o,m)
    int l = n0 >> 12, o = (n0 >> 10) & 3, m = (n0 >> 6) & 15;
    const float* c3b = c3 + m * 65536 + o * 16384 + l * 1024;   // [a][sp]
    const float* eb  = env + (size_t)blockIdx.x * 4096;         // [a][b]
    for (int i = t; i < 1024; i += 256) { c3s[i] = c3b[i]; svs[i] = sv[i]; }
    __syncthreads();
    float s = 0;
    int b = t & 63, ag = t >> 6;
#pragma unroll
    for (int g = 0; g < 16; g++) {
        int a = ag * 16 + g;
        float e = eb[a * 64 + b];
        float w = 0;
#pragma unroll
        for (int sp = 0; sp < 16; sp++) w += c3s[a * 16 + sp] * svs[b * 16 + sp];
        s += e * w;
    }
    red[t] = s; __syncthreads();
    for (int off = 128; off; off >>= 1) { if (t < off) red[t] += red[t + off]; __syncthreads(); }
    if (t == 0) atomicAdd(out, red[0]);
}

// ---- G1: envS (pre-split u32, LDS-staged once) x Sp1 -> t1 f16 panels ----
// grid 2048 = cc(2) x [l(16) o(4) m2(16)]; acc[2][4], two mt-passes.
__global__ __launch_bounds__(256, 4) void gemm_g1(const unsigned* __restrict__ envS,
                                                  const unsigned short* __restrict__ Sp1,
                                                  unsigned short* __restrict__ t1,
                                                  float scale) {
    __shared__ unsigned Bt[2][32 * 65];
    const int tid = threadIdx.x, lane = tid & 63, wave = tid >> 6;
    const int quad = lane >> 4, lr = lane & 15;
    const int cc = blockIdx.x >> 10, rid = blockIdx.x & 1023;
    const int l = rid >> 6, o = (rid >> 4) & 3, m2 = rid & 15;

    const unsigned* Bv = envS + (size_t)rid * 4096;
    const unsigned short* Sp1c = Sp1 + (size_t)cc * 32768;

    // stage BOTH k0 tiles once, single barrier
    {
        const uint4* src = (const uint4*)Bv;
        uint4 ur[4];
#pragma unroll
        for (int v = 0; v < 4; v++) ur[v] = src[v * 256 + tid];
#pragma unroll
        for (int v = 0; v < 4; v++) {
            int e = (v & 1) * 256 + tid;
            unsigned* p = &Bt[v >> 1][(e >> 4) * 65 + (e & 15) * 4];
            p[0] = ur[v].x; p[1] = ur[v].y; p[2] = ur[v].z; p[3] = ur[v].w;
        }
    }
    __syncthreads();

#pragma unroll
    for (int half = 0; half < 2; half++) {
        f32x4 acc[2][4];
#pragma unroll
        for (int i = 0; i < 2; i++)
#pragma unroll
            for (int j = 0; j < 4; j++)
#pragma unroll
                for (int r = 0; r < 4; r++) acc[i][j][r] = 0.0f;

#pragma unroll
        for (int k0 = 0; k0 < 2; k0++) {
            bf16x8 ah[2], al[2];
#pragma unroll
            for (int mt = 0; mt < 2; mt++) {
                int gmt = wave * 4 + half * 2 + mt;
                const unsigned short* ap = Sp1c + ((size_t)(k0 * 16 + gmt) * 2) * 512 + lane * 8;
                ah[mt] = *(const bf16x8*)ap;
                al[mt] = *(const bf16x8*)(ap + 512);
            }
#pragma unroll
            for (int nt = 0; nt < 4; nt++) {
                int nl = nt * 16 + lr;
                bf16x8 bh, bl;
#pragma unroll
                for (int j = 0; j < 8; j++) {
                    unsigned u = Bt[k0][(quad * 8 + j) * 65 + nl];
                    bh[j] = (short)(u & 0xffffu);
                    bl[j] = (short)(u >> 16);
                }
#pragma unroll
                for (int mt = 0; mt < 2; mt++) {
                    acc[mt][nt] = __builtin_amdgcn_mfma_f32_16x16x32_bf16(ah[mt], bh, acc[mt][nt], 0, 0, 0);
                    acc[mt][nt] = __builtin_amdgcn_mfma_f32_16x16x32_bf16(ah[mt], bl, acc[mt][nt], 0, 0, 0);
                    acc[mt][nt] = __builtin_amdgcn_mfma_f32_16x16x32_bf16(al[mt], bh, acc[mt][nt], 0, 0, 0);
                }
            }
        }

#pragma unroll
        for (int nt = 0; nt < 4; nt++) {
            int b = nt * 16 + lr;
#pragma unroll
            for (int r = 0; r < 4; r++) {
                int a4 = quad * 4 + r;
                us2 w;
                w[0] = f2h_bits(acc[0][nt][r] * scale);
                w[1] = f2h_bits(acc[1][nt][r] * scale);
                size_t addr = (size_t)cc * 16777216 +
                              (size_t)(o * 256 + m2 * 16 + a4) * 16384 +
                              (size_t)(l * 2 + (wave >> 1)) * 512 + b * 8 + (wave & 1) * 4 + half * 2;
                *(us2*)(t1 + addr) = w;
            }
        }
    }
}

// ---- G2: LDS-free f16 GEMM, acc[2][4], two mt-passes ---------------------
// grid 2048 = cc(2) x [o(4) m2(16) a4(16)]
__global__ __launch_bounds__(256, 4) void gemm_g2(const unsigned short* __restrict__ Bp,
                                                  const unsigned short* __restrict__ Ap,
                                                  unsigned short* __restrict__ Co) {
    const int tid = threadIdx.x, lane = tid & 63, wave = tid >> 6;
    const int quad = lane >> 4, lr = lane & 15;
    const int cc = blockIdx.x >> 10, rid = blockIdx.x & 1023;
    const int o = rid >> 8, m2 = (rid >> 4) & 15, a4 = rid & 15;
    const unsigned short* pb = Bp + (size_t)blockIdx.x * 16384;
    unsigned short* Cb = Co + (size_t)cc * 16777216;

#pragma unroll
    for (int half = 0; half < 2; half++) {
        f32x4 acc[2][4];
#pragma unroll
        for (int i = 0; i < 2; i++)
#pragma unroll
            for (int j = 0; j < 4; j++)
#pragma unroll
                for (int r = 0; r < 4; r++) acc[i][j][r] = 0.0f;

        f16x8 bf[2][4];
        auto loadB = [&](int k0, int buf) {
#pragma unroll
            for (int nt = 0; nt < 4; nt++) {
                int b = nt * 16 + lr;
                bf[buf][nt] = *(const f16x8*)(pb + ((size_t)(k0 * 4 + quad) << 9) + b * 8);
            }
        };
        loadB(0, 0);
#pragma unroll
        for (int k0 = 0; k0 < 8; k0++) {
            if (k0 + 1 < 8) loadB(k0 + 1, (k0 + 1) & 1);
            f16x8 ah[2];
#pragma unroll
            for (int mt = 0; mt < 2; mt++) {
                int gmt = wave * 4 + half * 2 + mt;
                ah[mt] = *(const f16x8*)(Ap + ((size_t)(k0 * 16 + gmt) * 2) * 512 + lane * 8);
            }
#pragma unroll
            for (int nt = 0; nt < 4; nt++)
#pragma unroll
                for (int mt = 0; mt < 2; mt++)
                    acc[mt][nt] = __builtin_amdgcn_mfma_f32_16x16x32_f16(
                        ah[mt], bf[k0 & 1][nt], acc[mt][nt], 0, 0, 0);
        }

#pragma unroll
        for (int nt = 0; nt < 4; nt++) {
            int b = nt * 16 + lr;
#pragma unroll
            for (int r = 0; r < 4; r++) {
                int L = quad * 4 + r;
                us2 w;
                w[0] = f2h_bits(acc[0][nt][r]);
                w[1] = f2h_bits(acc[1][nt][r]);
                size_t addr = (size_t)(L * 256 + m2 * 16 + a4) * 4096 +
                              (size_t)(o * 2 + (wave >> 1)) * 512 + b * 8 + (wave & 1) * 4 + half * 2;
                *(us2*)(Cb + addr) = w;
            }
        }
    }
}

// ---- G3: LDS-free f16 GEMM (unchanged, already light) --------------------
// grid 8192 = cc(2) x [L(16) m2(16) a4(16)]
template <int KT, int MT>
__global__ __launch_bounds__(256) void gemm_f16k3(const unsigned short* __restrict__ Bp,
                                                  const unsigned short* __restrict__ Ap,
                                                  unsigned short* __restrict__ Co) {
    const int tid = threadIdx.x, lane = tid & 63, wave = tid >> 6;
    const int quad = lane >> 4, lr = lane & 15;
    const int cc = blockIdx.x >> 12, rid = blockIdx.x & 4095;
    const unsigned short* pb = Bp + (size_t)blockIdx.x * (KT * 2048);
    unsigned short* Cb = Co + (size_t)cc * 16777216;

    f32x4 acc[4];
#pragma unroll
    for (int i = 0; i < 4; i++)
#pragma unroll
        for (int r = 0; r < 4; r++) acc[i][r] = 0.0f;

    f16x8 bf[2];
    auto loadB = [&](int k0, int buf) {
        int b = wave * 16 + lr;
        bf[buf] = *(const f16x8*)(pb + ((size_t)(k0 * 4 + quad) << 9) + b * 8);
    };
    loadB(0, 0);
#pragma unroll
    for (int k0 = 0; k0 < KT; k0++) {
        if (k0 + 1 < KT) loadB(k0 + 1, (k0 + 1) & 1);
        f16x8 ah[4];
#pragma unroll
        for (int mt = 0; mt < 4; mt++)
            ah[mt] = *(const f16x8*)(Ap + ((size_t)(k0 * MT + mt) * 2) * 512 + lane * 8);
#pragma unroll
        for (int mt = 0; mt < 4; mt++)
            acc[mt] = __builtin_amdgcn_mfma_f32_16x16x32_f16(
                ah[mt], bf[k0 & 1], acc[mt], 0, 0, 0);
    }

    const int L = rid >> 8, m2 = (rid >> 4) & 15, a4 = rid & 15;
    int b = wave * 16 + lr;
#pragma unroll
    for (int mt = 0; mt < 4; mt++) {
        us4 w;
#pragma unroll
        for (int r = 0; r < 4; r++) w[r] = f2h_bits(acc[mt][r]);
        size_t addr = (size_t)(mt * 256 + L * 16 + a4) * 16384 +
                      (size_t)(m2 * 2 + (quad >> 1)) * 512 + b * 8 + (quad & 1) * 4;
        *(us4*)(Cb + addr) = w;
    }
}

// ---- fused G4+G5: acc[2][4] x 2 passes; phase B per-wave barrier-free ----
// grid 2048 = cc(2) x [O2(4) L(16) a4(16)]; A0 = pair*32, A = A0+cc*16+a4
__global__ __launch_bounds__(256, 4) void gemm_g45(const unsigned short* __restrict__ Bp,
                                                   const unsigned short* __restrict__ Ap4,
                                                   const unsigned short* __restrict__ Sp5,
                                                   float* __restrict__ env, int A0,
                                                   float inv) {
    __shared__ unsigned SL[4 * 16 * 68];   // per-wave u32 slab / reduce buffer
    const int tid = threadIdx.x, lane = tid & 63, wave = tid >> 6;
    const int quad = lane >> 4, lr = lane & 15;
    const int cc = blockIdx.x >> 10, rid = blockIdx.x & 1023;
    const int O2 = rid >> 8, L = (rid >> 4) & 15, a4 = rid & 15;
    const unsigned short* pb = Bp + (size_t)blockIdx.x * 16384;
    unsigned* myslab = SL + wave * (16 * 68);

    f32x4 acc5[4];
#pragma unroll
    for (int nt = 0; nt < 4; nt++)
#pragma unroll
        for (int r = 0; r < 4; r++) acc5[nt][r] = 0.0f;

#pragma unroll
    for (int half = 0; half < 2; half++) {
        // phase A: this wave's mt pair (s = wave*4 + half*2 + {0,1})
        f32x4 acc[2][4];
#pragma unroll
        for (int i = 0; i < 2; i++)
#pragma unroll
            for (int j = 0; j < 4; j++)
#pragma unroll
                for (int r = 0; r < 4; r++) acc[i][j][r] = 0.0f;

        f16x8 bf[2][4];
        auto loadB = [&](int k0, int buf) {
#pragma unroll
            for (int nt = 0; nt < 4; nt++) {
                int b = nt * 16 + lr;
                bf[buf][nt] = *(const f16x8*)(pb + ((size_t)(k0 * 4 + quad) << 9) + b * 8);
            }
        };
        loadB(0, 0);
#pragma unroll
        for (int k0 = 0; k0 < 8; k0++) {
            if (k0 + 1 < 8) loadB(k0 + 1, (k0 + 1) & 1);
            f16x8 ah[2];
#pragma unroll
            for (int mt = 0; mt < 2; mt++) {
                int gmt = wave * 4 + half * 2 + mt;
                ah[mt] = *(const f16x8*)(Ap4 + ((size_t)(k0 * 16 + gmt) * 2) * 512 + lane * 8);
            }
#pragma unroll
            for (int nt = 0; nt < 4; nt++)
#pragma unroll
                for (int mt = 0; mt < 2; mt++)
                    acc[mt][nt] = __builtin_amdgcn_mfma_f32_16x16x32_f16(
                        ah[mt], bf[k0 & 1][nt], acc[mt][nt], 0, 0, 0);
        }

        // phase B: contract this half's two s-rows, barrier-free
#pragma unroll
        for (int mtp = 0; mtp < 2; mtp++) {
            int s = wave * 4 + half * 2 + mtp;
            // deposit own slab [M2=16][b=64 pad 68] (u32 split-pair)
#pragma unroll
            for (int nt = 0; nt < 4; nt++)
#pragma unroll
                for (int r = 0; r < 4; r++)
                    myslab[(quad * 4 + r) * 68 + nt * 16 + lr] = split2(acc[mtp][nt][r]);
            // same-wave cross-lane LDS dependency: drain LDS pipe, pin ordering
            asm volatile("s_waitcnt lgkmcnt(0)" ::: "memory");
#pragma unroll
            for (int h = 0; h < 2; h++) {
                const unsigned* sp = &myslab[lr * 68 + h * 32 + quad * 8];
                uint4 u0 = *(const uint4*)sp;
                uint4 u1 = *(const uint4*)(sp + 4);
                bf16x8 th, tl;
                th[0] = (short)(u0.x & 0xffff); tl[0] = (short)(u0.x >> 16);
                th[1] = (short)(u0.y & 0xffff); tl[1] = (short)(u0.y >> 16);
                th[2] = (short)(u0.z & 0xffff); tl[2] = (short)(u0.z >> 16);
                th[3] = (short)(u0.w & 0xffff); tl[3] = (short)(u0.w >> 16);
                th[4] = (short)(u1.x & 0xffff); tl[4] = (short)(u1.x >> 16);
                th[5] = (short)(u1.y & 0xffff); tl[5] = (short)(u1.y >> 16);
                th[6] = (short)(u1.z & 0xffff); tl[6] = (short)(u1.z >> 16);
                th[7] = (short)(u1.w & 0xffff); tl[7] = (short)(u1.w >> 16);
                int kg = s * 2 + h;
#pragma unroll
                for (int nt = 0; nt < 4; nt++) {
                    const unsigned short* bp =
                        Sp5 + ((size_t)(kg * 4 + nt) * 2) * 512 + lane * 8;
                    bf16x8 sh = *(const bf16x8*)bp;
                    bf16x8 sl = *(const bf16x8*)(bp + 512);
                    acc5[nt] = __builtin_amdgcn_mfma_f32_16x16x32_bf16(th, sh, acc5[nt], 0, 0, 0);
                    acc5[nt] = __builtin_amdgcn_mfma_f32_16x16x32_bf16(th, sl, acc5[nt], 0, 0, 0);
                    acc5[nt] = __builtin_amdgcn_mfma_f32_16x16x32_bf16(tl, sh, acc5[nt], 0, 0, 0);
                }
            }
        }
    }

    // cross-wave reduce: one barrier, float view of SL
    __syncthreads();
    float* red = (float*)SL;
#pragma unroll
    for (int nt = 0; nt < 4; nt++)
#pragma unroll
        for (int r = 0; r < 4; r++)
            red[wave * 1088 + (quad * 4 + r) * 68 + nt * 16 + lr] = acc5[nt][r];
    __syncthreads();
#pragma unroll
    for (int r = 0; r < 4; r++) {
        int M2 = quad * 4 + r, Bc = wave * 16 + lr;
        float v = red[M2 * 68 + Bc] + red[1088 + M2 * 68 + Bc] +
                  red[2176 + M2 * 68 + Bc] + red[3264 + M2 * 68 + Bc];
        env[(size_t)(L * 64 + O2 * 16 + M2) * 4096 + (A0 + cc * 16 + a4) * 64 + Bc] = v * inv;
    }
}

extern "C" void kernel_launch(void* const* d_in, const int* in_sizes, int n_in,
                              void* d_out, int out_size, void* d_ws, size_t ws_size,
                              hipStream_t stream) {
    const float* state = (const float*)d_in[0];   // [8,64,16,64]
    const float* layer = (const float*)d_in[1];   // [1,8,16,16,16,16]
    const float* oper  = (const float*)d_in[2];   // [8,4,16,16,4]
    float* out = (float*)d_out;

    // F 64MiB | P 128MiB | envA 16MiB | envB 16MiB | envS 16MiB | packs | sv
    const size_t need = 16777216ull * 4 + 33554432ull * 4 + 3ull * 4194304ull * 4 +
                        (4ull * 1048576ull + 65536ull) * 2ull + 4096ull;
    if (ws_size < need) {
        write_diag_kernel<<<1, 64, 0, stream>>>(out, (float)ws_size);
        return;
    }
    float* F    = (float*)d_ws;                          // SCR fp32 / T2 u16
    unsigned* P = (unsigned*)(F + 16777216);             // T1 + T3 (u16)
    float* envA = (float*)(P + 33554432);
    float* envB = envA + 4194304;
    unsigned* envS = (unsigned*)(envB + 4194304);
    unsigned short* Ap2 = (unsigned short*)(envS + 4194304);
    unsigned short* Ap4 = Ap2 + 1048576;
    unsigned short* Sp1 = Ap4 + 1048576;
    unsigned short* Sp5 = Sp1 + 1048576;
    unsigned short* Op3 = Sp5 + 1048576;
    float* sv = (float*)(Op3 + 65536);
    float* SCR = F;
    unsigned short* T1 = (unsigned short*)P;
    unsigned short* T3 = T1 + 33554432;
    unsigned short* T2 = (unsigned short*)F;

    prep_apack<<<256, 256, 0, stream>>>(layer, Ap2, Ap4);
    prep_spack1<<<256, 256, 0, stream>>>(state, Sp1);
    prep_spack5<<<256, 256, 0, stream>>>(state, Sp5);
    prep_opack3<<<16, 256, 0, stream>>>(oper, Op3);
    prep_sv<<<4, 256, 0, stream>>>(state, sv);

    // site 0 -> envB (exact fp32)
    s0_g2<<<64, 256, 0, stream>>>(state, layer, SCR);
    s0_g3<<<256, 256, 0, stream>>>(SCR, oper, SCR + 16384);
    s0_g4<<<4096, 256, 0, stream>>>(SCR + 16384, layer, SCR + 81920);
    s0_env<<<16384, 256, 0, stream>>>(SCR + 81920, state, envB);

    for (int q = 1; q < 7; q++) {
        float* ein  = (q & 1) ? envB : envA;
        float* eout = (q & 1) ? envA : envB;
        float scl = (float)(1u << (16 + 2 * q));   // exact power of 2
        float inv = 1.0f / scl;
        env_split_k<<<4096, 256, 0, stream>>>(ein, envS);
        for (int p = 0; p < 2; p++) {
            gemm_g1<<<2048, 256, 0, stream>>>(
                envS, Sp1 + (size_t)(q * 4 + p * 2) * 32768, T1, scl);
            gemm_g2<<<2048, 256, 0, stream>>>(
                T1, Ap2 + (size_t)q * 131072, T2);
            gemm_f16k3<2, 4><<<8192, 256, 0, stream>>>(
                T2, Op3 + (size_t)q * 8192, T3);
            gemm_g45<<<2048, 256, 0, stream>>>(
                T3, Ap4 + (size_t)q * 131072, Sp5 + (size_t)q * 131072, eout, p * 32, inv);
        }
    }

    // site 7: out = <env7 (in envB), w>
    s7_c1<<<64, 256, 0, stream>>>(state, layer, SCR);
    s7_c2<<<256, 256, 0, stream>>>(SCR, oper, SCR + 16384);
    s7_c3<<<4096, 256, 0, stream>>>(SCR + 16384, layer, SCR + 81920);
    zero_out<<<1, 64, 0, stream>>>(out);
    s7_fused<<<1024, 256, 0, stream>>>(envB, SCR + 81920, sv, out);
}

// Round 3
// 1809.639 us; speedup vs baseline: 1.4173x; 1.4173x over previous
//
#include <hip/hip_runtime.h>

// ---------------------------------------------------------------------------
// <psi|U^dag O U|psi>, NQ=8, r=64 d=16 rl=16 ro=4.
// R15 = R13 (full revert of R14's spill disaster: forcing 4 waves/SIMD via
// launch_bounds(256,4)+acc[2][4] made the compiler cap arch VGPRs at 64 and
// spill ~64MB to scratch: WRITE_SIZE 8->74MB, MfmaUtil 21->13%)
//   + ONE register-neutral change in gemm_g45 phase B: deposit ALL FOUR
//   mtp slabs first (LDS 17.4->69.6 KB/block; occupancy already reg-capped
//   at 2 blocks/CU so 139KB/CU fits), then a single lgkmcnt(0) drain, then
//   the 4 read+MFMA passes back-to-back so LDS reads / Sp5 loads of slice
//   k+1 overlap MFMAs of slice k. Same MFMA order => bit-identical.
// Everything else identical to R13 (c-pairing, env pre-split, f16
// intermediates + power-of-2 scaling, fp32 boundary chains).
// ---------------------------------------------------------------------------

typedef __attribute__((ext_vector_type(8))) short bf16x8;
typedef __attribute__((ext_vector_type(8))) _Float16 f16x8;
typedef __attribute__((ext_vector_type(4))) float f32x4;
typedef __attribute__((ext_vector_type(4))) unsigned short us4;

static __device__ __forceinline__ unsigned short f2bf(float x) {
    union { float f; unsigned u; } a; a.f = x;
    return (unsigned short)((a.u + 0x7FFF + ((a.u >> 16) & 1)) >> 16);
}
static __device__ __forceinline__ float bf2f(unsigned short h) {
    union { unsigned u; float f; } a; a.u = (unsigned)h << 16; return a.f;
}
static __device__ __forceinline__ unsigned split2(float x) {
    unsigned short h = f2bf(x);
    unsigned short l = f2bf(x - bf2f(h));
    return (unsigned)h | ((unsigned)l << 16);
}
static __device__ __forceinline__ unsigned short f2h_bits(float x) {
    union { _Float16 h; unsigned short u; } c; c.h = (_Float16)x; return c.u;
}
static __device__ __forceinline__ float h2f_bits(unsigned short u) {
    union { unsigned short u; _Float16 h; } c; c.u = u; return (float)c.h;
}

__global__ void write_diag_kernel(float* out, float v) {
    if (threadIdx.x == 0 && blockIdx.x == 0) out[0] = v;
}
__global__ void zero_out(float* o) {
    if (threadIdx.x == 0 && blockIdx.x == 0) o[0] = 0.0f;
}

// ---- A-operand fragment packs -------------------------------------------
__global__ void prep_apack(const float* __restrict__ layer,
                           unsigned short* __restrict__ Ap2,
                           unsigned short* __restrict__ Ap4) {
    int idx = blockIdx.x * 256 + threadIdx.x;   // 65536
    int q = idx >> 13, k0 = (idx >> 10) & 7, mt = (idx >> 6) & 15, lane = idx & 63;
    int quad = lane >> 4, r = lane & 15;
    unsigned short h2[8], l2[8], h4[8], l4[8];
#pragma unroll
    for (int j = 0; j < 8; j++) {
        int k = k0 * 32 + quad * 8 + j;
        int m = mt * 16 + r;
        float v2 = layer[(size_t)q * 65536 +
                         (size_t)((((k >> 4) * 16 + (m >> 4)) * 16 + (k & 15)) * 16 + (m & 15))];
        float v4 = layer[(size_t)q * 65536 +
                         (size_t)((((k >> 4) * 16 + (k & 15)) * 16 + (m >> 4)) * 16 + (m & 15))];
        h2[j] = f2h_bits(v2); l2[j] = f2h_bits(v2 - h2f_bits(h2[j]));
        h4[j] = f2h_bits(v4); l4[j] = f2h_bits(v4 - h2f_bits(h4[j]));
    }
    size_t base = ((size_t)((q * 8 + k0) * 16 + mt) * 2) * 512 + lane * 8;
    *(us4*)(Ap2 + base)       = *(us4*)&h2[0];
    *(us4*)(Ap2 + base + 4)   = *(us4*)&h2[4];
    *(us4*)(Ap2 + base + 512) = *(us4*)&l2[0];
    *(us4*)(Ap2 + base + 516) = *(us4*)&l2[4];
    *(us4*)(Ap4 + base)       = *(us4*)&h4[0];
    *(us4*)(Ap4 + base + 4)   = *(us4*)&h4[4];
    *(us4*)(Ap4 + base + 512) = *(us4*)&l4[0];
    *(us4*)(Ap4 + base + 516) = *(us4*)&l4[4];
}

__global__ void prep_spack1(const float* __restrict__ state,
                            unsigned short* __restrict__ Sp1) {
    int idx = blockIdx.x * 256 + threadIdx.x;   // 65536
    int q = idx >> 13, c = (idx >> 11) & 3, k0 = (idx >> 10) & 1,
        mt = (idx >> 6) & 15, lane = idx & 63;
    int quad = lane >> 4, lr = lane & 15;
    unsigned short h[8], l[8];
#pragma unroll
    for (int j = 0; j < 8; j++) {
        int k = k0 * 32 + quad * 8 + j;
        float v = state[(size_t)q * 65536 + (size_t)(k * 16 + mt) * 64 + c * 16 + lr];
        h[j] = f2bf(v); l[j] = f2bf(v - bf2f(h[j]));
    }
    size_t base = (size_t)(q * 4 + c) * 32768 + ((size_t)(k0 * 16 + mt) * 2) * 512 + lane * 8;
    *(us4*)(Sp1 + base)       = *(us4*)&h[0];
    *(us4*)(Sp1 + base + 4)   = *(us4*)&h[4];
    *(us4*)(Sp1 + base + 512) = *(us4*)&l[0];
    *(us4*)(Sp1 + base + 516) = *(us4*)&l[4];
}

__global__ void prep_spack5(const float* __restrict__ state,
                            unsigned short* __restrict__ Sp5) {
    int idx = blockIdx.x * 256 + threadIdx.x;   // 65536
    int q = idx >> 13, k0 = (idx >> 8) & 31, mt = (idx >> 6) & 3, lane = idx & 63;
    int quad = lane >> 4, lr = lane & 15;
    unsigned short h[8], l[8];
#pragma unroll
    for (int j = 0; j < 8; j++) {
        int k = k0 * 32 + quad * 8 + j;   // k = s*64+b
        int s = k >> 6, b = k & 63;
        float v = state[(size_t)q * 65536 + (size_t)(b * 16 + s) * 64 + mt * 16 + lr];
        h[j] = f2bf(v); l[j] = f2bf(v - bf2f(h[j]));
    }
    size_t base = (size_t)q * 131072 + ((size_t)(k0 * 4 + mt) * 2) * 512 + lane * 8;
    *(us4*)(Sp5 + base)       = *(us4*)&h[0];
    *(us4*)(Sp5 + base + 4)   = *(us4*)&h[4];
    *(us4*)(Sp5 + base + 512) = *(us4*)&l[0];
    *(us4*)(Sp5 + base + 516) = *(us4*)&l[4];
}

__global__ void prep_opack3(const float* __restrict__ oper,
                            unsigned short* __restrict__ Op3) {
    int idx = blockIdx.x * 256 + threadIdx.x;   // 4096
    int q = idx >> 9, k0 = (idx >> 8) & 1, mt = (idx >> 6) & 3, lane = idx & 63;
    int quad = lane >> 4, lr = lane & 15;
    unsigned short h[8], l[8];
#pragma unroll
    for (int j = 0; j < 8; j++) {
        int k = k0 * 32 + quad * 8 + j;
        int m = mt * 16 + lr;
        float v = oper[(size_t)q * 4096 + (size_t)(k * 16 + (m & 15)) * 4 + (m >> 4)];
        h[j] = f2h_bits(v); l[j] = f2h_bits(v - h2f_bits(h[j]));
    }
    size_t base = (size_t)q * 8192 + ((size_t)(k0 * 4 + mt) * 2) * 512 + lane * 8;
    *(us4*)(Op3 + base)       = *(us4*)&h[0];
    *(us4*)(Op3 + base + 4)   = *(us4*)&h[4];
    *(us4*)(Op3 + base + 512) = *(us4*)&l[0];
    *(us4*)(Op3 + base + 516) = *(us4*)&l[4];
}

// ---- env fp32 -> packed u32 (bf16 hi | lo<<16), once per site -----------
__global__ void env_split_k(const float* __restrict__ env, unsigned* __restrict__ envS) {
    int t = blockIdx.x * 256 + threadIdx.x;   // 1048576 x float4
    float4 v = ((const float4*)env)[t];
    uint4 o;
    o.x = split2(v.x); o.y = split2(v.y); o.z = split2(v.z); o.w = split2(v.w);
    ((uint4*)envS)[t] = o;
}

// ---- site 0 (env0 = delta): env1 built by a cheap chain (fp32 exact) ----
__global__ void s0_g2(const float* __restrict__ state, const float* __restrict__ layer,
                      float* __restrict__ g2) {
    int t = blockIdx.x * 256 + threadIdx.x;          // 16384: [A][j][L]
    int A = t >> 8, j = (t >> 4) & 15, L = t & 15;
    float s = 0;
    for (int i = 0; i < 16; i++) s += state[i * 64 + A] * layer[(j * 16 + i) * 16 + L];
    g2[t] = s;
}
__global__ void s0_g3(const float* __restrict__ g2, const float* __restrict__ oper,
                      float* __restrict__ g3) {
    int t = blockIdx.x * 256 + threadIdx.x;          // 65536: [A][L][k][O]
    int A = t >> 10, L = (t >> 6) & 15, k = (t >> 2) & 15, O = t & 3;
    float s = 0;
    for (int j = 0; j < 16; j++) s += g2[A * 256 + j * 16 + L] * oper[(j * 16 + k) * 4 + O];
    g3[t] = s;
}
__global__ void s0_g4(const float* __restrict__ g3, const float* __restrict__ layer,
                      float* __restrict__ g4) {
    int t = blockIdx.x * 256 + threadIdx.x;          // 1048576: [A][L][O][s][M]
    int A = t >> 14, L = (t >> 10) & 15, O = (t >> 8) & 3, sp = (t >> 4) & 15, M = t & 15;
    float s = 0;
    for (int k = 0; k < 16; k++)
        s += g3[A * 1024 + L * 64 + k * 4 + O] * layer[(k * 16 + sp) * 16 + M];
    g4[t] = s;
}
__global__ void s0_env(const float* __restrict__ g4, const float* __restrict__ state,
                       float* __restrict__ env) {
    int t = blockIdx.x * 256 + threadIdx.x;          // 4194304
    int A = t >> 16, L = (t >> 12) & 15, O = (t >> 10) & 3, M = (t >> 6) & 15, B = t & 63;
    float s = 0;
    for (int sp = 0; sp < 16; sp++)
        s += g4[A * 16384 + L * 1024 + O * 256 + sp * 16 + M] * state[sp * 64 + B];
    env[(size_t)(L * 64 + O * 16 + M) * 4096 + A * 64 + B] = s;
}

// ---- site 7 chain (fp32) + fused dot ------------------------------------
__global__ void s7_c1(const float* __restrict__ state, const float* __restrict__ layer,
                      float* __restrict__ c1) {
    int t = blockIdx.x * 256 + threadIdx.x;          // 16384: [l][a][j]
    int l = t >> 10, a = (t >> 4) & 63, j = t & 15;
    float s = 0;
    for (int i = 0; i < 16; i++)
        s += state[7 * 65536 + (a * 16 + i) * 64] * layer[7 * 65536 + ((l * 16 + j) * 16 + i) * 16];
    c1[t] = s;
}
__global__ void s7_c2(const float* __restrict__ c1, const float* __restrict__ oper,
                      float* __restrict__ c2) {
    int t = blockIdx.x * 256 + threadIdx.x;          // 65536: [o][l][a][k]
    int o = t >> 14, l = (t >> 10) & 15, a = (t >> 4) & 63, k = t & 15;
    float s = 0;
    for (int j = 0; j < 16; j++)
        s += c1[l * 1024 + a * 16 + j] * oper[7 * 4096 + ((o * 16 + j) * 16 + k) * 4];
    c2[t] = s;
}
__global__ void s7_c3(const float* __restrict__ c2, const float* __restrict__ layer,
                      float* __restrict__ c3) {
    int t = blockIdx.x * 256 + threadIdx.x;          // 1048576: [m][o][l][a][s]
    int m = t >> 16, o = (t >> 14) & 3, l = (t >> 10) & 15, a = (t >> 4) & 63, sp = t & 15;
    float s = 0;
    for (int k = 0; k < 16; k++)
        s += c2[o * 16384 + l * 1024 + a * 16 + k] *
             layer[7 * 65536 + ((m * 16 + k) * 16 + sp) * 16];
    c3[t] = s;
}
__global__ void prep_sv(const float* __restrict__ state, float* __restrict__ sv) {
    int t = blockIdx.x * 256 + threadIdx.x;          // 1024: [b][sp]
    sv[t] = state[7 * 65536 + t * 64];
}
__global__ __launch_bounds__(256) void s7_fused(const float* __restrict__ env,
                                                const float* __restrict__ c3,
                                                const float* __restrict__ sv,
                                                float* __restrict__ out) {
    __shared__ float c3s[1024], svs[1024], red[256];
    int t = threadIdx.x;
    int n0 = blockIdx.x * 64;            // region=(l,o,m)
    int l = n0 >> 12, o = (n0 >> 10) & 3, m = (n0 >> 6) & 15;
    const float* c3b = c3 + m * 65536 + o * 16384 + l * 1024;   // [a][sp]
    const float* eb  = env + (size_t)blockIdx.x * 4096;         // [a][b]
    for (int i = t; i < 1024; i += 256) { c3s[i] = c3b[i]; svs[i] = sv[i]; }
    __syncthreads();
    float s = 0;
    int b = t & 63, ag = t >> 6;
#pragma unroll
    for (int g = 0; g < 16; g++) {
        int a = ag * 16 + g;
        float e = eb[a * 64 + b];
        float w = 0;
#pragma unroll
        for (int sp = 0; sp < 16; sp++) w += c3s[a * 16 + sp] * svs[b * 16 + sp];
        s += e * w;
    }
    red[t] = s; __syncthreads();
    for (int off = 128; off; off >>= 1) { if (t < off) red[t] += red[t + off]; __syncthreads(); }
    if (t == 0) atomicAdd(out, red[0]);
}

// ---- G1: envS (pre-split u32, LDS-staged) x Sp1 -> t1 f16 panels ---------
// grid 2048 = cc(2) x [l(16) o(4) m2(16)]
__global__ __launch_bounds__(256) void gemm_g1(const unsigned* __restrict__ envS,
                                               const unsigned short* __restrict__ Sp1,
                                               unsigned short* __restrict__ t1,
                                               float scale) {
    __shared__ unsigned Bt[32 * 65];
    const int tid = threadIdx.x, lane = tid & 63, wave = tid >> 6;
    const int quad = lane >> 4, lr = lane & 15;
    const int cc = blockIdx.x >> 10, rid = blockIdx.x & 1023;
    const int l = rid >> 6, o = (rid >> 4) & 3, m2 = rid & 15;

    f32x4 acc[4][4];
#pragma unroll
    for (int i = 0; i < 4; i++)
#pragma unroll
        for (int j = 0; j < 4; j++)
#pragma unroll
            for (int r = 0; r < 4; r++) acc[i][j][r] = 0.0f;

    const unsigned* Bv = envS + (size_t)rid * 4096;
    const unsigned short* Sp1c = Sp1 + (size_t)cc * 32768;
    uint4 ur[2];
    auto load_tile = [&](int k0) {
        const uint4* src = (const uint4*)(Bv + k0 * 2048);
        ur[0] = src[tid];
        ur[1] = src[256 + tid];
    };
    auto store_tile = [&]() {
#pragma unroll
        for (int v = 0; v < 2; v++) {
            int e = v * 256 + tid;
            unsigned* p = &Bt[(e >> 4) * 65 + (e & 15) * 4];
            p[0] = ur[v].x; p[1] = ur[v].y; p[2] = ur[v].z; p[3] = ur[v].w;
        }
    };

    load_tile(0);
    store_tile();
    for (int k0 = 0; k0 < 2; k0++) {
        __syncthreads();
        if (k0 + 1 < 2) load_tile(k0 + 1);
        bf16x8 ah[4], al[4];
#pragma unroll
        for (int mt = 0; mt < 4; mt++) {
            int gmt = wave * 4 + mt;
            const unsigned short* ap = Sp1c + ((size_t)(k0 * 16 + gmt) * 2) * 512 + lane * 8;
            ah[mt] = *(const bf16x8*)ap;
            al[mt] = *(const bf16x8*)(ap + 512);
        }
#pragma unroll
        for (int nt = 0; nt < 4; nt++) {
            int nl = nt * 16 + lr;
            bf16x8 bh, bl;
#pragma unroll
            for (int j = 0; j < 8; j++) {
                unsigned u = Bt[(quad * 8 + j) * 65 + nl];
                bh[j] = (short)(u & 0xffffu);
                bl[j] = (short)(u >> 16);
            }
#pragma unroll
            for (int mt = 0; mt < 4; mt++) {
                acc[mt][nt] = __builtin_amdgcn_mfma_f32_16x16x32_bf16(ah[mt], bh, acc[mt][nt], 0, 0, 0);
                acc[mt][nt] = __builtin_amdgcn_mfma_f32_16x16x32_bf16(ah[mt], bl, acc[mt][nt], 0, 0, 0);
                acc[mt][nt] = __builtin_amdgcn_mfma_f32_16x16x32_bf16(al[mt], bh, acc[mt][nt], 0, 0, 0);
            }
        }
        __syncthreads();
        if (k0 + 1 < 2) store_tile();
    }

#pragma unroll
    for (int nt = 0; nt < 4; nt++) {
        int b = nt * 16 + lr;
#pragma unroll
        for (int r = 0; r < 4; r++) {
            int a4 = quad * 4 + r;
            us4 w;
#pragma unroll
            for (int mt = 0; mt < 4; mt++) w[mt] = f2h_bits(acc[mt][nt][r] * scale);
            size_t addr = (size_t)cc * 16777216 +
                          (size_t)(o * 256 + m2 * 16 + a4) * 16384 +
                          (size_t)(l * 2 + (wave >> 1)) * 512 + b * 8 + (wave & 1) * 4;
            *(us4*)(t1 + addr) = w;
        }
    }
}

// ---- LDS-free f16 GEMM (G2: SM=2, G3: SM=3), c-paired --------------------
// SM=2: grid 2048 = cc(2) x [o(4) m2(16) a4(16)]
// SM=3: grid 8192 = cc(2) x [L(16) m2(16) a4(16)]
template <int KT, int MT, int WS, int SM>
__global__ __launch_bounds__(256) void gemm_f16k(const unsigned short* __restrict__ Bp,
                                                 const unsigned short* __restrict__ Ap,
                                                 unsigned short* __restrict__ Co) {
    constexpr int NT = (WS == 0) ? 4 : 1;
    constexpr int RB = (SM == 2) ? 10 : 12;
    const int tid = threadIdx.x, lane = tid & 63, wave = tid >> 6;
    const int quad = lane >> 4, lr = lane & 15;
    const int cc = blockIdx.x >> RB, rid = blockIdx.x & ((1 << RB) - 1);
    const unsigned short* pb = Bp + (size_t)blockIdx.x * (KT * 2048);
    unsigned short* Cb = Co + (size_t)cc * 16777216;

    f32x4 acc[4][NT];
#pragma unroll
    for (int i = 0; i < 4; i++)
#pragma unroll
        for (int j = 0; j < NT; j++)
#pragma unroll
            for (int r = 0; r < 4; r++) acc[i][j][r] = 0.0f;

    f16x8 bf[2][NT];
    auto loadB = [&](int k0, int buf) {
#pragma unroll
        for (int nt = 0; nt < NT; nt++) {
            int b = (WS == 0) ? (nt * 16 + lr) : (wave * 16 + lr);
            bf[buf][nt] = *(const f16x8*)(pb + ((size_t)(k0 * 4 + quad) << 9) + b * 8);
        }
    };
    loadB(0, 0);
#pragma unroll
    for (int k0 = 0; k0 < KT; k0++) {
        if (k0 + 1 < KT) loadB(k0 + 1, (k0 + 1) & 1);
        f16x8 ah[4];
#pragma unroll
        for (int mt = 0; mt < 4; mt++) {
            int gmt = (WS == 0) ? (wave * 4 + mt) : mt;
            ah[mt] = *(const f16x8*)(Ap + ((size_t)(k0 * MT + gmt) * 2) * 512 + lane * 8);
        }
#pragma unroll
        for (int nt = 0; nt < NT; nt++)
#pragma unroll
            for (int mt = 0; mt < 4; mt++)
                acc[mt][nt] = __builtin_amdgcn_mfma_f32_16x16x32_f16(
                    ah[mt], bf[k0 & 1][nt], acc[mt][nt], 0, 0, 0);
    }

    if constexpr (SM == 2) {
        const int o = rid >> 8, m2 = (rid >> 4) & 15, a4 = rid & 15;
#pragma unroll
        for (int nt = 0; nt < NT; nt++) {
            int b = nt * 16 + lr;
#pragma unroll
            for (int r = 0; r < 4; r++) {
                int L = quad * 4 + r;
                us4 w;
#pragma unroll
                for (int mt = 0; mt < 4; mt++) w[mt] = f2h_bits(acc[mt][nt][r]);
                size_t addr = (size_t)(L * 256 + m2 * 16 + a4) * 4096 +
                              (size_t)(o * 2 + (wave >> 1)) * 512 + b * 8 + (wave & 1) * 4;
                *(us4*)(Cb + addr) = w;
            }
        }
    } else {
        const int L = rid >> 8, m2 = (rid >> 4) & 15, a4 = rid & 15;
        int b = wave * 16 + lr;
#pragma unroll
        for (int mt = 0; mt < 4; mt++) {
            us4 w;
#pragma unroll
            for (int r = 0; r < 4; r++) w[r] = f2h_bits(acc[mt][0][r]);
            size_t addr = (size_t)(mt * 256 + L * 16 + a4) * 16384 +
                          (size_t)(m2 * 2 + (quad >> 1)) * 512 + b * 8 + (quad & 1) * 4;
            *(us4*)(Cb + addr) = w;
        }
    }
}

// ---- fused G4+G5: phase A LDS-free f16; phase B per-wave barrier-free ----
// grid 2048 = cc(2) x [O2(4) L(16) a4(16)]; A0 = pair*32, A = A0+cc*16+a4
// R15: phase B deposits all 4 mtp slabs, ONE lgkmcnt(0) drain, then 4
// read+MFMA passes back-to-back (reads of pass k+1 overlap MFMAs of k).
__global__ __launch_bounds__(256) void gemm_g45(const unsigned short* __restrict__ Bp,
                                                const unsigned short* __restrict__ Ap4,
                                                const unsigned short* __restrict__ Sp5,
                                                float* __restrict__ env, int A0,
                                                float inv) {
    __shared__ unsigned SL[4 * 4 * 16 * 68];   // [wave][mtp][16][68] / reduce buffer
    const int tid = threadIdx.x, lane = tid & 63, wave = tid >> 6;
    const int quad = lane >> 4, lr = lane & 15;
    const int cc = blockIdx.x >> 10, rid = blockIdx.x & 1023;
    const int O2 = rid >> 8, L = (rid >> 4) & 15, a4 = rid & 15;
    const unsigned short* pb = Bp + (size_t)blockIdx.x * 16384;

    f32x4 acc[4][4];
#pragma unroll
    for (int i = 0; i < 4; i++)
#pragma unroll
        for (int j = 0; j < 4; j++)
#pragma unroll
            for (int r = 0; r < 4; r++) acc[i][j][r] = 0.0f;

    f16x8 bf[2][4];
    auto loadB = [&](int k0, int buf) {
#pragma unroll
        for (int nt = 0; nt < 4; nt++) {
            int b = nt * 16 + lr;
            bf[buf][nt] = *(const f16x8*)(pb + ((size_t)(k0 * 4 + quad) << 9) + b * 8);
        }
    };
    loadB(0, 0);
#pragma unroll
    for (int k0 = 0; k0 < 8; k0++) {
        if (k0 + 1 < 8) loadB(k0 + 1, (k0 + 1) & 1);
        f16x8 ah[4];
#pragma unroll
        for (int mt = 0; mt < 4; mt++) {
            int gmt = wave * 4 + mt;
            ah[mt] = *(const f16x8*)(Ap4 + ((size_t)(k0 * 16 + gmt) * 2) * 512 + lane * 8);
        }
#pragma unroll
        for (int nt = 0; nt < 4; nt++)
#pragma unroll
            for (int mt = 0; mt < 4; mt++)
                acc[mt][nt] = __builtin_amdgcn_mfma_f32_16x16x32_f16(
                    ah[mt], bf[k0 & 1][nt], acc[mt][nt], 0, 0, 0);
    }

    // phase B: per-wave k-quarter (s = 4*wave..4*wave+3), barrier-free.
    unsigned* myslab = SL + wave * (4 * 16 * 68);
    f32x4 acc5[4];
#pragma unroll
    for (int nt = 0; nt < 4; nt++)
#pragma unroll
        for (int r = 0; r < 4; r++) acc5[nt][r] = 0.0f;

    // deposit ALL FOUR slabs [mtp][M2=16][b=64 pad 68] (u32 split-pair)
#pragma unroll
    for (int mtp = 0; mtp < 4; mtp++)
#pragma unroll
        for (int nt = 0; nt < 4; nt++)
#pragma unroll
            for (int r = 0; r < 4; r++)
                myslab[mtp * 1088 + (quad * 4 + r) * 68 + nt * 16 + lr] =
                    split2(acc[mtp][nt][r]);
    // same-wave cross-lane LDS dependency: single drain, pin ordering
    asm volatile("s_waitcnt lgkmcnt(0)" ::: "memory");

#pragma unroll
    for (int mtp = 0; mtp < 4; mtp++) {
        int s = wave * 4 + mtp;
#pragma unroll
        for (int h = 0; h < 2; h++) {
            const unsigned* sp = &myslab[mtp * 1088 + lr * 68 + h * 32 + quad * 8];
            uint4 u0 = *(const uint4*)sp;
            uint4 u1 = *(const uint4*)(sp + 4);
            bf16x8 th, tl;
            th[0] = (short)(u0.x & 0xffff); tl[0] = (short)(u0.x >> 16);
            th[1] = (short)(u0.y & 0xffff); tl[1] = (short)(u0.y >> 16);
            th[2] = (short)(u0.z & 0xffff); tl[2] = (short)(u0.z >> 16);
            th[3] = (short)(u0.w & 0xffff); tl[3] = (short)(u0.w >> 16);
            th[4] = (short)(u1.x & 0xffff); tl[4] = (short)(u1.x >> 16);
            th[5] = (short)(u1.y & 0xffff); tl[5] = (short)(u1.y >> 16);
            th[6] = (short)(u1.z & 0xffff); tl[6] = (short)(u1.z >> 16);
            th[7] = (short)(u1.w & 0xffff); tl[7] = (short)(u1.w >> 16);
            int kg = s * 2 + h;
#pragma unroll
            for (int nt = 0; nt < 4; nt++) {
                const unsigned short* bp =
                    Sp5 + ((size_t)(kg * 4 + nt) * 2) * 512 + lane * 8;
                bf16x8 sh = *(const bf16x8*)bp;
                bf16x8 sl = *(const bf16x8*)(bp + 512);
                acc5[nt] = __builtin_amdgcn_mfma_f32_16x16x32_bf16(th, sh, acc5[nt], 0, 0, 0);
                acc5[nt] = __builtin_amdgcn_mfma_f32_16x16x32_bf16(th, sl, acc5[nt], 0, 0, 0);
                acc5[nt] = __builtin_amdgcn_mfma_f32_16x16x32_bf16(tl, sh, acc5[nt], 0, 0, 0);
            }
        }
    }

    // cross-wave reduce: one barrier, float view of SL
    __syncthreads();
    float* red = (float*)SL;
#pragma unroll
    for (int nt = 0; nt < 4; nt++)
#pragma unroll
        for (int r = 0; r < 4; r++)
            red[wave * 1088 + (quad * 4 + r) * 68 + nt * 16 + lr] = acc5[nt][r];
    __syncthreads();
#pragma unroll
    for (int r = 0; r < 4; r++) {
        int M2 = quad * 4 + r, Bc = wave * 16 + lr;
        float v = red[M2 * 68 + Bc] + red[1088 + M2 * 68 + Bc] +
                  red[2176 + M2 * 68 + Bc] + red[3264 + M2 * 68 + Bc];
        env[(size_t)(L * 64 + O2 * 16 + M2) * 4096 + (A0 + cc * 16 + a4) * 64 + Bc] = v * inv;
    }
}

extern "C" void kernel_launch(void* const* d_in, const int* in_sizes, int n_in,
                              void* d_out, int out_size, void* d_ws, size_t ws_size,
                              hipStream_t stream) {
    const float* state = (const float*)d_in[0];   // [8,64,16,64]
    const float* layer = (const float*)d_in[1];   // [1,8,16,16,16,16]
    const float* oper  = (const float*)d_in[2];   // [8,4,16,16,4]
    float* out = (float*)d_out;

    // F 64MiB | P 128MiB | envA 16MiB | envB 16MiB | envS 16MiB | packs | sv
    const size_t need = 16777216ull * 4 + 33554432ull * 4 + 3ull * 4194304ull * 4 +
                        (4ull * 1048576ull + 65536ull) * 2ull + 4096ull;
    if (ws_size < need) {
        write_diag_kernel<<<1, 64, 0, stream>>>(out, (float)ws_size);
        return;
    }
    float* F    = (float*)d_ws;                          // SCR fp32 / T2 u16
    unsigned* P = (unsigned*)(F + 16777216);             // T1 + T3 (u16)
    float* envA = (float*)(P + 33554432);
    float* envB = envA + 4194304;
    unsigned* envS = (unsigned*)(envB + 4194304);
    unsigned short* Ap2 = (unsigned short*)(envS + 4194304);
    unsigned short* Ap4 = Ap2 + 1048576;
    unsigned short* Sp1 = Ap4 + 1048576;
    unsigned short* Sp5 = Sp1 + 1048576;
    unsigned short* Op3 = Sp5 + 1048576;
    float* sv = (float*)(Op3 + 65536);
    float* SCR = F;
    unsigned short* T1 = (unsigned short*)P;
    unsigned short* T3 = T1 + 33554432;
    unsigned short* T2 = (unsigned short*)F;

    prep_apack<<<256, 256, 0, stream>>>(layer, Ap2, Ap4);
    prep_spack1<<<256, 256, 0, stream>>>(state, Sp1);
    prep_spack5<<<256, 256, 0, stream>>>(state, Sp5);
    prep_opack3<<<16, 256, 0, stream>>>(oper, Op3);
    prep_sv<<<4, 256, 0, stream>>>(state, sv);

    // site 0 -> envB (exact fp32)
    s0_g2<<<64, 256, 0, stream>>>(state, layer, SCR);
    s0_g3<<<256, 256, 0, stream>>>(SCR, oper, SCR + 16384);
    s0_g4<<<4096, 256, 0, stream>>>(SCR + 16384, layer, SCR + 81920);
    s0_env<<<16384, 256, 0, stream>>>(SCR + 81920, state, envB);

    for (int q = 1; q < 7; q++) {
        float* ein  = (q & 1) ? envB : envA;
        float* eout = (q & 1) ? envA : envB;
        float scl = (float)(1u << (16 + 2 * q));   // exact power of 2
        float inv = 1.0f / scl;
        env_split_k<<<4096, 256, 0, stream>>>(ein, envS);
        for (int p = 0; p < 2; p++) {
            gemm_g1<<<2048, 256, 0, stream>>>(
                envS, Sp1 + (size_t)(q * 4 + p * 2) * 32768, T1, scl);
            gemm_f16k<8, 16, 0, 2><<<2048, 256, 0, stream>>>(
                T1, Ap2 + (size_t)q * 131072, T2);
            gemm_f16k<2, 4, 1, 3><<<8192, 256, 0, stream>>>(
                T2, Op3 + (size_t)q * 8192, T3);
            gemm_g45<<<2048, 256, 0, stream>>>(
                T3, Ap4 + (size_t)q * 131072, Sp5 + (size_t)q * 131072, eout, p * 32, inv);
        }
    }

    // site 7: out = <env7 (in envB), w>
    s7_c1<<<64, 256, 0, stream>>>(state, layer, SCR);
    s7_c2<<<256, 256, 0, stream>>>(SCR, oper, SCR + 16384);
    s7_c3<<<4096, 256, 0, stream>>>(SCR + 16384, layer, SCR + 81920);
    zero_out<<<1, 64, 0, stream>>>(out);
    s7_fused<<<1024, 256, 0, stream>>>(envB, SCR + 81920, sv, out);
}

// Round 4
// 1639.767 us; speedup vs baseline: 1.5641x; 1.1036x over previous
//
#include <hip/hip_runtime.h>

// ---------------------------------------------------------------------------
// <psi|U^dag O U|psi>, NQ=8, r=64 d=16 rl=16 ro=4.
// R16 = R13/R15 + memory-level-parallelism overhaul (occupancy is reg-capped
// at 2 waves/SIMD and R14 proved forcing it causes spills; so attack latency
// with ILP/MLP instead, bit-identical MFMA order):
//  (a) g45 + G2: stage the full 32KB B panel to LDS up front with 8x
//      global_load_lds(16B)/thread (one latency exposure per block, 2048
//      lines in flight), then ds_read_b128 it (bank-balanced).
//  (b) depth-2 A-panel prefetch (ah[3][4]) in g45-A/G2; depth-1 in G1/G3;
//      depth-1 pipeline of the 8 Sp5 loads in g45 phase B (vmcnt loads are
//      not blocked by the lgkmcnt drain).
//  (c) g45 emits split-u32 env directly (ping-pong envS0/envS1 reusing the
//      old envA slot; fp32 env written only at q=6 for s7). env_split runs
//      once (after site 0). -5 launches, -160MB traffic.
// ---------------------------------------------------------------------------

typedef __attribute__((ext_vector_type(8))) short bf16x8;
typedef __attribute__((ext_vector_type(8))) _Float16 f16x8;
typedef __attribute__((ext_vector_type(4))) float f32x4;
typedef __attribute__((ext_vector_type(4))) unsigned short us4;

static __device__ __forceinline__ unsigned short f2bf(float x) {
    union { float f; unsigned u; } a; a.f = x;
    return (unsigned short)((a.u + 0x7FFF + ((a.u >> 16) & 1)) >> 16);
}
static __device__ __forceinline__ float bf2f(unsigned short h) {
    union { unsigned u; float f; } a; a.u = (unsigned)h << 16; return a.f;
}
static __device__ __forceinline__ unsigned split2(float x) {
    unsigned short h = f2bf(x);
    unsigned short l = f2bf(x - bf2f(h));
    return (unsigned)h | ((unsigned)l << 16);
}
static __device__ __forceinline__ unsigned short f2h_bits(float x) {
    union { _Float16 h; unsigned short u; } c; c.h = (_Float16)x; return c.u;
}
static __device__ __forceinline__ float h2f_bits(unsigned short u) {
    union { unsigned short u; _Float16 h; } c; c.u = u; return (float)c.h;
}
// async global->LDS, 16B per lane; lds base must be wave-uniform.
static __device__ __forceinline__ void gl_lds16(const unsigned short* g,
                                                unsigned short* l) {
    __builtin_amdgcn_global_load_lds(
        (const __attribute__((address_space(1))) unsigned int*)g,
        (__attribute__((address_space(3))) unsigned int*)l, 16, 0, 0);
}

__global__ void write_diag_kernel(float* out, float v) {
    if (threadIdx.x == 0 && blockIdx.x == 0) out[0] = v;
}
__global__ void zero_out(float* o) {
    if (threadIdx.x == 0 && blockIdx.x == 0) o[0] = 0.0f;
}

// ---- A-operand fragment packs -------------------------------------------
__global__ void prep_apack(const float* __restrict__ layer,
                           unsigned short* __restrict__ Ap2,
                           unsigned short* __restrict__ Ap4) {
    int idx = blockIdx.x * 256 + threadIdx.x;   // 65536
    int q = idx >> 13, k0 = (idx >> 10) & 7, mt = (idx >> 6) & 15, lane = idx & 63;
    int quad = lane >> 4, r = lane & 15;
    unsigned short h2[8], l2[8], h4[8], l4[8];
#pragma unroll
    for (int j = 0; j < 8; j++) {
        int k = k0 * 32 + quad * 8 + j;
        int m = mt * 16 + r;
        float v2 = layer[(size_t)q * 65536 +
                         (size_t)((((k >> 4) * 16 + (m >> 4)) * 16 + (k & 15)) * 16 + (m & 15))];
        float v4 = layer[(size_t)q * 65536 +
                         (size_t)((((k >> 4) * 16 + (k & 15)) * 16 + (m >> 4)) * 16 + (m & 15))];
        h2[j] = f2h_bits(v2); l2[j] = f2h_bits(v2 - h2f_bits(h2[j]));
        h4[j] = f2h_bits(v4); l4[j] = f2h_bits(v4 - h2f_bits(h4[j]));
    }
    size_t base = ((size_t)((q * 8 + k0) * 16 + mt) * 2) * 512 + lane * 8;
    *(us4*)(Ap2 + base)       = *(us4*)&h2[0];
    *(us4*)(Ap2 + base + 4)   = *(us4*)&h2[4];
    *(us4*)(Ap2 + base + 512) = *(us4*)&l2[0];
    *(us4*)(Ap2 + base + 516) = *(us4*)&l2[4];
    *(us4*)(Ap4 + base)       = *(us4*)&h4[0];
    *(us4*)(Ap4 + base + 4)   = *(us4*)&h4[4];
    *(us4*)(Ap4 + base + 512) = *(us4*)&l4[0];
    *(us4*)(Ap4 + base + 516) = *(us4*)&l4[4];
}

__global__ void prep_spack1(const float* __restrict__ state,
                            unsigned short* __restrict__ Sp1) {
    int idx = blockIdx.x * 256 + threadIdx.x;   // 65536
    int q = idx >> 13, c = (idx >> 11) & 3, k0 = (idx >> 10) & 1,
        mt = (idx >> 6) & 15, lane = idx & 63;
    int quad = lane >> 4, lr = lane & 15;
    unsigned short h[8], l[8];
#pragma unroll
    for (int j = 0; j < 8; j++) {
        int k = k0 * 32 + quad * 8 + j;
        float v = state[(size_t)q * 65536 + (size_t)(k * 16 + mt) * 64 + c * 16 + lr];
        h[j] = f2bf(v); l[j] = f2bf(v - bf2f(h[j]));
    }
    size_t base = (size_t)(q * 4 + c) * 32768 + ((size_t)(k0 * 16 + mt) * 2) * 512 + lane * 8;
    *(us4*)(Sp1 + base)       = *(us4*)&h[0];
    *(us4*)(Sp1 + base + 4)   = *(us4*)&h[4];
    *(us4*)(Sp1 + base + 512) = *(us4*)&l[0];
    *(us4*)(Sp1 + base + 516) = *(us4*)&l[4];
}

__global__ void prep_spack5(const float* __restrict__ state,
                            unsigned short* __restrict__ Sp5) {
    int idx = blockIdx.x * 256 + threadIdx.x;   // 65536
    int q = idx >> 13, k0 = (idx >> 8) & 31, mt = (idx >> 6) & 3, lane = idx & 63;
    int quad = lane >> 4, lr = lane & 15;
    unsigned short h[8], l[8];
#pragma unroll
    for (int j = 0; j < 8; j++) {
        int k = k0 * 32 + quad * 8 + j;   // k = s*64+b
        int s = k >> 6, b = k & 63;
        float v = state[(size_t)q * 65536 + (size_t)(b * 16 + s) * 64 + mt * 16 + lr];
        h[j] = f2bf(v); l[j] = f2bf(v - bf2f(h[j]));
    }
    size_t base = (size_t)q * 131072 + ((size_t)(k0 * 4 + mt) * 2) * 512 + lane * 8;
    *(us4*)(Sp5 + base)       = *(us4*)&h[0];
    *(us4*)(Sp5 + base + 4)   = *(us4*)&h[4];
    *(us4*)(Sp5 + base + 512) = *(us4*)&l[0];
    *(us4*)(Sp5 + base + 516) = *(us4*)&l[4];
}

__global__ void prep_opack3(const float* __restrict__ oper,
                            unsigned short* __restrict__ Op3) {
    int idx = blockIdx.x * 256 + threadIdx.x;   // 4096
    int q = idx >> 9, k0 = (idx >> 8) & 1, mt = (idx >> 6) & 3, lane = idx & 63;
    int quad = lane >> 4, lr = lane & 15;
    unsigned short h[8], l[8];
#pragma unroll
    for (int j = 0; j < 8; j++) {
        int k = k0 * 32 + quad * 8 + j;
        int m = mt * 16 + lr;
        float v = oper[(size_t)q * 4096 + (size_t)(k * 16 + (m & 15)) * 4 + (m >> 4)];
        h[j] = f2h_bits(v); l[j] = f2h_bits(v - h2f_bits(h[j]));
    }
    size_t base = (size_t)q * 8192 + ((size_t)(k0 * 4 + mt) * 2) * 512 + lane * 8;
    *(us4*)(Op3 + base)       = *(us4*)&h[0];
    *(us4*)(Op3 + base + 4)   = *(us4*)&h[4];
    *(us4*)(Op3 + base + 512) = *(us4*)&l[0];
    *(us4*)(Op3 + base + 516) = *(us4*)&l[4];
}

// ---- env fp32 -> packed u32 (bf16 hi | lo<<16), once after site 0 -------
__global__ void env_split_k(const float* __restrict__ env, unsigned* __restrict__ envS) {
    int t = blockIdx.x * 256 + threadIdx.x;   // 1048576 x float4
    float4 v = ((const float4*)env)[t];
    uint4 o;
    o.x = split2(v.x); o.y = split2(v.y); o.z = split2(v.z); o.w = split2(v.w);
    ((uint4*)envS)[t] = o;
}

// ---- site 0 (env0 = delta): env1 built by a cheap chain (fp32 exact) ----
__global__ void s0_g2(const float* __restrict__ state, const float* __restrict__ layer,
                      float* __restrict__ g2) {
    int t = blockIdx.x * 256 + threadIdx.x;          // 16384: [A][j][L]
    int A = t >> 8, j = (t >> 4) & 15, L = t & 15;
    float s = 0;
    for (int i = 0; i < 16; i++) s += state[i * 64 + A] * layer[(j * 16 + i) * 16 + L];
    g2[t] = s;
}
__global__ void s0_g3(const float* __restrict__ g2, const float* __restrict__ oper,
                      float* __restrict__ g3) {
    int t = blockIdx.x * 256 + threadIdx.x;          // 65536: [A][L][k][O]
    int A = t >> 10, L = (t >> 6) & 15, k = (t >> 2) & 15, O = t & 3;
    float s = 0;
    for (int j = 0; j < 16; j++) s += g2[A * 256 + j * 16 + L] * oper[(j * 16 + k) * 4 + O];
    g3[t] = s;
}
__global__ void s0_g4(const float* __restrict__ g3, const float* __restrict__ layer,
                      float* __restrict__ g4) {
    int t = blockIdx.x * 256 + threadIdx.x;          // 1048576: [A][L][O][s][M]
    int A = t >> 14, L = (t >> 10) & 15, O = (t >> 8) & 3, sp = (t >> 4) & 15, M = t & 15;
    float s = 0;
    for (int k = 0; k < 16; k++)
        s += g3[A * 1024 + L * 64 + k * 4 + O] * layer[(k * 16 + sp) * 16 + M];
    g4[t] = s;
}
__global__ void s0_env(const float* __restrict__ g4, const float* __restrict__ state,
                       float* __restrict__ env) {
    int t = blockIdx.x * 256 + threadIdx.x;          // 4194304
    int A = t >> 16, L = (t >> 12) & 15, O = (t >> 10) & 3, M = (t >> 6) & 15, B = t & 63;
    float s = 0;
    for (int sp = 0; sp < 16; sp++)
        s += g4[A * 16384 + L * 1024 + O * 256 + sp * 16 + M] * state[sp * 64 + B];
    env[(size_t)(L * 64 + O * 16 + M) * 4096 + A * 64 + B] = s;
}

// ---- site 7 chain (fp32) + fused dot ------------------------------------
__global__ void s7_c1(const float* __restrict__ state, const float* __restrict__ layer,
                      float* __restrict__ c1) {
    int t = blockIdx.x * 256 + threadIdx.x;          // 16384: [l][a][j]
    int l = t >> 10, a = (t >> 4) & 63, j = t & 15;
    float s = 0;
    for (int i = 0; i < 16; i++)
        s += state[7 * 65536 + (a * 16 + i) * 64] * layer[7 * 65536 + ((l * 16 + j) * 16 + i) * 16];
    c1[t] = s;
}
__global__ void s7_c2(const float* __restrict__ c1, const float* __restrict__ oper,
                      float* __restrict__ c2) {
    int t = blockIdx.x * 256 + threadIdx.x;          // 65536: [o][l][a][k]
    int o = t >> 14, l = (t >> 10) & 15, a = (t >> 4) & 63, k = t & 15;
    float s = 0;
    for (int j = 0; j < 16; j++)
        s += c1[l * 1024 + a * 16 + j] * oper[7 * 4096 + ((o * 16 + j) * 16 + k) * 4];
    c2[t] = s;
}
__global__ void s7_c3(const float* __restrict__ c2, const float* __restrict__ layer,
                      float* __restrict__ c3) {
    int t = blockIdx.x * 256 + threadIdx.x;          // 1048576: [m][o][l][a][s]
    int m = t >> 16, o = (t >> 14) & 3, l = (t >> 10) & 15, a = (t >> 4) & 63, sp = t & 15;
    float s = 0;
    for (int k = 0; k < 16; k++)
        s += c2[o * 16384 + l * 1024 + a * 16 + k] *
             layer[7 * 65536 + ((m * 16 + k) * 16 + sp) * 16];
    c3[t] = s;
}
__global__ void prep_sv(const float* __restrict__ state, float* __restrict__ sv) {
    int t = blockIdx.x * 256 + threadIdx.x;          // 1024: [b][sp]
    sv[t] = state[7 * 65536 + t * 64];
}
__global__ __launch_bounds__(256) void s7_fused(const float* __restrict__ env,
                                                const float* __restrict__ c3,
                                                const float* __restrict__ sv,
                                                float* __restrict__ out) {
    __shared__ float c3s[1024], svs[1024], red[256];
    int t = threadIdx.x;
    int n0 = blockIdx.x * 64;            // region=(l,o,m)
    int l = n0 >> 12, o = (n0 >> 10) & 3, m = (n0 >> 6) & 15;
    const float* c3b = c3 + m * 65536 + o * 16384 + l * 1024;   // [a][sp]
    const float* eb  = env + (size_t)blockIdx.x * 4096;         // [a][b]
    for (int i = t; i < 1024; i += 256) { c3s[i] = c3b[i]; svs[i] = sv[i]; }
    __syncthreads();
    float s = 0;
    int b = t & 63, ag = t >> 6;
#pragma unroll
    for (int g = 0; g < 16; g++) {
        int a = ag * 16 + g;
        float e = eb[a * 64 + b];
        float w = 0;
#pragma unroll
        for (int sp = 0; sp < 16; sp++) w += c3s[a * 16 + sp] * svs[b * 16 + sp];
        s += e * w;
    }
    red[t] = s; __syncthreads();
    for (int off = 128; off; off >>= 1) { if (t < off) red[t] += red[t + off]; __syncthreads(); }
    if (t == 0) atomicAdd(out, red[0]);
}

// ---- G1: envS (pre-split u32, LDS-staged) x Sp1 -> t1 f16 panels ---------
// grid 2048 = cc(2) x [l(16) o(4) m2(16)]; A operands prefetched 1 k0 ahead.
__global__ __launch_bounds__(256) void gemm_g1(const unsigned* __restrict__ envS,
                                               const unsigned short* __restrict__ Sp1,
                                               unsigned short* __restrict__ t1,
                                               float scale) {
    __shared__ unsigned Bt[32 * 65];
    const int tid = threadIdx.x, lane = tid & 63, wave = tid >> 6;
    const int quad = lane >> 4, lr = lane & 15;
    const int cc = blockIdx.x >> 10, rid = blockIdx.x & 1023;
    const int l = rid >> 6, o = (rid >> 4) & 3, m2 = rid & 15;

    f32x4 acc[4][4];
#pragma unroll
    for (int i = 0; i < 4; i++)
#pragma unroll
        for (int j = 0; j < 4; j++)
#pragma unroll
            for (int r = 0; r < 4; r++) acc[i][j][r] = 0.0f;

    const unsigned* Bv = envS + (size_t)rid * 4096;
    const unsigned short* Sp1c = Sp1 + (size_t)cc * 32768;
    uint4 ur[2];
    auto load_tile = [&](int k0) {
        const uint4* src = (const uint4*)(Bv + k0 * 2048);
        ur[0] = src[tid];
        ur[1] = src[256 + tid];
    };
    auto store_tile = [&]() {
#pragma unroll
        for (int v = 0; v < 2; v++) {
            int e = v * 256 + tid;
            unsigned* p = &Bt[(e >> 4) * 65 + (e & 15) * 4];
            p[0] = ur[v].x; p[1] = ur[v].y; p[2] = ur[v].z; p[3] = ur[v].w;
        }
    };

    bf16x8 ahb[2][4], alb[2][4];
    auto loadA = [&](int k0, int buf) {
#pragma unroll
        for (int mt = 0; mt < 4; mt++) {
            int gmt = wave * 4 + mt;
            const unsigned short* ap = Sp1c + ((size_t)(k0 * 16 + gmt) * 2) * 512 + lane * 8;
            ahb[buf][mt] = *(const bf16x8*)ap;
            alb[buf][mt] = *(const bf16x8*)(ap + 512);
        }
    };

    load_tile(0);
    loadA(0, 0);
    store_tile();
#pragma unroll
    for (int k0 = 0; k0 < 2; k0++) {
        __syncthreads();
        if (k0 + 1 < 2) { load_tile(k0 + 1); loadA(k0 + 1, 1); }
#pragma unroll
        for (int nt = 0; nt < 4; nt++) {
            int nl = nt * 16 + lr;
            bf16x8 bh, bl;
#pragma unroll
            for (int j = 0; j < 8; j++) {
                unsigned u = Bt[(quad * 8 + j) * 65 + nl];
                bh[j] = (short)(u & 0xffffu);
                bl[j] = (short)(u >> 16);
            }
#pragma unroll
            for (int mt = 0; mt < 4; mt++) {
                acc[mt][nt] = __builtin_amdgcn_mfma_f32_16x16x32_bf16(ahb[k0][mt], bh, acc[mt][nt], 0, 0, 0);
                acc[mt][nt] = __builtin_amdgcn_mfma_f32_16x16x32_bf16(ahb[k0][mt], bl, acc[mt][nt], 0, 0, 0);
                acc[mt][nt] = __builtin_amdgcn_mfma_f32_16x16x32_bf16(alb[k0][mt], bh, acc[mt][nt], 0, 0, 0);
            }
        }
        __syncthreads();
        if (k0 + 1 < 2) store_tile();
    }

#pragma unroll
    for (int nt = 0; nt < 4; nt++) {
        int b = nt * 16 + lr;
#pragma unroll
        for (int r = 0; r < 4; r++) {
            int a4 = quad * 4 + r;
            us4 w;
#pragma unroll
            for (int mt = 0; mt < 4; mt++) w[mt] = f2h_bits(acc[mt][nt][r] * scale);
            size_t addr = (size_t)cc * 16777216 +
                          (size_t)(o * 256 + m2 * 16 + a4) * 16384 +
                          (size_t)(l * 2 + (wave >> 1)) * 512 + b * 8 + (wave & 1) * 4;
            *(us4*)(t1 + addr) = w;
        }
    }
}

// ---- G2: B panel LDS-staged via global_load_lds; A depth-2 prefetch ------
// grid 2048 = cc(2) x [o(4) m2(16) a4(16)]
__global__ __launch_bounds__(256) void gemm_g2(const unsigned short* __restrict__ Bp,
                                               const unsigned short* __restrict__ Ap,
                                               unsigned short* __restrict__ Co) {
    __shared__ __align__(16) unsigned short Bs[16384];   // 32KB panel
    const int tid = threadIdx.x, lane = tid & 63, wave = tid >> 6;
    const int quad = lane >> 4, lr = lane & 15;
    const int cc = blockIdx.x >> 10, rid = blockIdx.x & 1023;
    const int o = rid >> 8, m2 = (rid >> 4) & 15, a4 = rid & 15;
    const unsigned short* pb = Bp + (size_t)blockIdx.x * 16384;
    unsigned short* Cb = Co + (size_t)cc * 16777216;

#pragma unroll
    for (int i = 0; i < 8; i++)
        gl_lds16(pb + i * 2048 + tid * 8, Bs + i * 2048 + wave * 512);

    f32x4 acc[4][4];
#pragma unroll
    for (int i = 0; i < 4; i++)
#pragma unroll
        for (int j = 0; j < 4; j++)
#pragma unroll
            for (int r = 0; r < 4; r++) acc[i][j][r] = 0.0f;

    f16x8 ah[3][4];
    auto loadA = [&](int k0, int buf) {
#pragma unroll
        for (int mt = 0; mt < 4; mt++) {
            int gmt = wave * 4 + mt;
            ah[buf][mt] = *(const f16x8*)(Ap + ((size_t)(k0 * 16 + gmt) * 2) * 512 + lane * 8);
        }
    };
    loadA(0, 0);
    loadA(1, 1);

    asm volatile("s_waitcnt vmcnt(0)" ::: "memory");
    __syncthreads();

#pragma unroll
    for (int k0 = 0; k0 < 8; k0++) {
        if (k0 + 2 < 8) loadA(k0 + 2, (k0 + 2) % 3);
        f16x8 bfr[4];
#pragma unroll
        for (int nt = 0; nt < 4; nt++)
            bfr[nt] = *(const f16x8*)(Bs + (k0 * 4 + quad) * 512 + (nt * 16 + lr) * 8);
#pragma unroll
        for (int nt = 0; nt < 4; nt++)
#pragma unroll
            for (int mt = 0; mt < 4; mt++)
                acc[mt][nt] = __builtin_amdgcn_mfma_f32_16x16x32_f16(
                    ah[k0 % 3][mt], bfr[nt], acc[mt][nt], 0, 0, 0);
    }

#pragma unroll
    for (int nt = 0; nt < 4; nt++) {
        int b = nt * 16 + lr;
#pragma unroll
        for (int r = 0; r < 4; r++) {
            int L = quad * 4 + r;
            us4 w;
#pragma unroll
            for (int mt = 0; mt < 4; mt++) w[mt] = f2h_bits(acc[mt][nt][r]);
            size_t addr = (size_t)(L * 256 + m2 * 16 + a4) * 4096 +
                          (size_t)(o * 2 + (wave >> 1)) * 512 + b * 8 + (wave & 1) * 4;
            *(us4*)(Cb + addr) = w;
        }
    }
}

// ---- G3: tiny-K f16 GEMM, all loads issued up front ----------------------
// grid 8192 = cc(2) x [L(16) m2(16) a4(16)]
__global__ __launch_bounds__(256) void gemm_g3(const unsigned short* __restrict__ Bp,
                                               const unsigned short* __restrict__ Ap,
                                               unsigned short* __restrict__ Co) {
    const int tid = threadIdx.x, lane = tid & 63, wave = tid >> 6;
    const int quad = lane >> 4, lr = lane & 15;
    const int cc = blockIdx.x >> 12, rid = blockIdx.x & 4095;
    const unsigned short* pb = Bp + (size_t)blockIdx.x * 4096;
    unsigned short* Cb = Co + (size_t)cc * 16777216;
    const int b = wave * 16 + lr;

    f16x8 bf0 = *(const f16x8*)(pb + ((size_t)(0 * 4 + quad) << 9) + b * 8);
    f16x8 bf1 = *(const f16x8*)(pb + ((size_t)(1 * 4 + quad) << 9) + b * 8);
    f16x8 ah0[4], ah1[4];
#pragma unroll
    for (int mt = 0; mt < 4; mt++)
        ah0[mt] = *(const f16x8*)(Ap + ((size_t)(0 * 4 + mt) * 2) * 512 + lane * 8);
#pragma unroll
    for (int mt = 0; mt < 4; mt++)
        ah1[mt] = *(const f16x8*)(Ap + ((size_t)(1 * 4 + mt) * 2) * 512 + lane * 8);

    f32x4 acc[4];
#pragma unroll
    for (int i = 0; i < 4; i++)
#pragma unroll
        for (int r = 0; r < 4; r++) acc[i][r] = 0.0f;

#pragma unroll
    for (int mt = 0; mt < 4; mt++)
        acc[mt] = __builtin_amdgcn_mfma_f32_16x16x32_f16(ah0[mt], bf0, acc[mt], 0, 0, 0);
#pragma unroll
    for (int mt = 0; mt < 4; mt++)
        acc[mt] = __builtin_amdgcn_mfma_f32_16x16x32_f16(ah1[mt], bf1, acc[mt], 0, 0, 0);

    const int L = rid >> 8, m2 = (rid >> 4) & 15, a4 = rid & 15;
#pragma unroll
    for (int mt = 0; mt < 4; mt++) {
        us4 w;
#pragma unroll
        for (int r = 0; r < 4; r++) w[r] = f2h_bits(acc[mt][r]);
        size_t addr = (size_t)(mt * 256 + L * 16 + a4) * 16384 +
                      (size_t)(m2 * 2 + (quad >> 1)) * 512 + b * 8 + (quad & 1) * 4;
        *(us4*)(Cb + addr) = w;
    }
}

// ---- fused G4+G5: B LDS-staged, A depth-2, Sp5 depth-1 pipeline ----------
// grid 2048 = cc(2) x [O2(4) L(16) a4(16)]; A0 = pair*32, A = A0+cc*16+a4
// Writes split-u32 env (envSo) always; fp32 env only when wf32 (q==6).
__global__ __launch_bounds__(256) void gemm_g45(const unsigned short* __restrict__ Bp,
                                                const unsigned short* __restrict__ Ap4,
                                                const unsigned short* __restrict__ Sp5,
                                                float* __restrict__ env,
                                                unsigned* __restrict__ envSo,
                                                int A0, float inv, int wf32) {
    __shared__ __align__(16) unsigned short Bs[16384];   // 32KB B panel
    __shared__ unsigned SL[4 * 16 * 68];                 // slab / reduce buffer
    const int tid = threadIdx.x, lane = tid & 63, wave = tid >> 6;
    const int quad = lane >> 4, lr = lane & 15;
    const int cc = blockIdx.x >> 10, rid = blockIdx.x & 1023;
    const int O2 = rid >> 8, L = (rid >> 4) & 15, a4 = rid & 15;
    const unsigned short* pb = Bp + (size_t)blockIdx.x * 16384;

#pragma unroll
    for (int i = 0; i < 8; i++)
        gl_lds16(pb + i * 2048 + tid * 8, Bs + i * 2048 + wave * 512);

    f32x4 acc[4][4];
#pragma unroll
    for (int i = 0; i < 4; i++)
#pragma unroll
        for (int j = 0; j < 4; j++)
#pragma unroll
            for (int r = 0; r < 4; r++) acc[i][j][r] = 0.0f;

    f16x8 ah[3][4];
    auto loadA = [&](int k0, int buf) {
#pragma unroll
        for (int mt = 0; mt < 4; mt++) {
            int gmt = wave * 4 + mt;
            ah[buf][mt] = *(const f16x8*)(Ap4 + ((size_t)(k0 * 16 + gmt) * 2) * 512 + lane * 8);
        }
    };
    loadA(0, 0);
    loadA(1, 1);

    asm volatile("s_waitcnt vmcnt(0)" ::: "memory");
    __syncthreads();

#pragma unroll
    for (int k0 = 0; k0 < 8; k0++) {
        if (k0 + 2 < 8) loadA(k0 + 2, (k0 + 2) % 3);
        f16x8 bfr[4];
#pragma unroll
        for (int nt = 0; nt < 4; nt++)
            bfr[nt] = *(const f16x8*)(Bs + (k0 * 4 + quad) * 512 + (nt * 16 + lr) * 8);
#pragma unroll
        for (int nt = 0; nt < 4; nt++)
#pragma unroll
            for (int mt = 0; mt < 4; mt++)
                acc[mt][nt] = __builtin_amdgcn_mfma_f32_16x16x32_f16(
                    ah[k0 % 3][mt], bfr[nt], acc[mt][nt], 0, 0, 0);
    }

    // phase B: per-wave k-quarter (s = 4*wave..4*wave+3), barrier-free.
    unsigned* myslab = SL + wave * (16 * 68);
    f32x4 acc5[4];
#pragma unroll
    for (int nt = 0; nt < 4; nt++)
#pragma unroll
        for (int r = 0; r < 4; r++) acc5[nt][r] = 0.0f;

    // Sp5 depth-1 pipeline: step = mtp*2+h, buffers by step parity.
    bf16x8 s5h[2][4], s5l[2][4];
    auto loadS5 = [&](int step, int buf) {
        int kg = (wave * 4 + (step >> 1)) * 2 + (step & 1);
#pragma unroll
        for (int nt = 0; nt < 4; nt++) {
            const unsigned short* bp = Sp5 + ((size_t)(kg * 4 + nt) * 2) * 512 + lane * 8;
            s5h[buf][nt] = *(const bf16x8*)bp;
            s5l[buf][nt] = *(const bf16x8*)(bp + 512);
        }
    };
    loadS5(0, 0);

#pragma unroll
    for (int mtp = 0; mtp < 4; mtp++) {
        // deposit own slab [M2=16][b=64 pad 68] (u32 split-pair)
#pragma unroll
        for (int nt = 0; nt < 4; nt++)
#pragma unroll
            for (int r = 0; r < 4; r++)
                myslab[(quad * 4 + r) * 68 + nt * 16 + lr] = split2(acc[mtp][nt][r]);
        // same-wave cross-lane LDS dependency: drain LDS pipe (vmcnt loads
        // from loadS5 stay in flight - lgkmcnt does not wait on them)
        asm volatile("s_waitcnt lgkmcnt(0)" ::: "memory");
#pragma unroll
        for (int h = 0; h < 2; h++) {
            const int step = mtp * 2 + h;
            const unsigned* sp = &myslab[lr * 68 + h * 32 + quad * 8];
            uint4 u0 = *(const uint4*)sp;
            uint4 u1 = *(const uint4*)(sp + 4);
            bf16x8 th, tl;
            th[0] = (short)(u0.x & 0xffff); tl[0] = (short)(u0.x >> 16);
            th[1] = (short)(u0.y & 0xffff); tl[1] = (short)(u0.y >> 16);
            th[2] = (short)(u0.z & 0xffff); tl[2] = (short)(u0.z >> 16);
            th[3] = (short)(u0.w & 0xffff); tl[3] = (short)(u0.w >> 16);
            th[4] = (short)(u1.x & 0xffff); tl[4] = (short)(u1.x >> 16);
            th[5] = (short)(u1.y & 0xffff); tl[5] = (short)(u1.y >> 16);
            th[6] = (short)(u1.z & 0xffff); tl[6] = (short)(u1.z >> 16);
            th[7] = (short)(u1.w & 0xffff); tl[7] = (short)(u1.w >> 16);
            if (step + 1 < 8) loadS5(step + 1, (step + 1) & 1);
#pragma unroll
            for (int nt = 0; nt < 4; nt++) {
                acc5[nt] = __builtin_amdgcn_mfma_f32_16x16x32_bf16(th, s5h[step & 1][nt], acc5[nt], 0, 0, 0);
                acc5[nt] = __builtin_amdgcn_mfma_f32_16x16x32_bf16(th, s5l[step & 1][nt], acc5[nt], 0, 0, 0);
                acc5[nt] = __builtin_amdgcn_mfma_f32_16x16x32_bf16(tl, s5h[step & 1][nt], acc5[nt], 0, 0, 0);
            }
        }
    }

    // cross-wave reduce: one barrier, float view of SL
    __syncthreads();
    float* red = (float*)SL;
#pragma unroll
    for (int nt = 0; nt < 4; nt++)
#pragma unroll
        for (int r = 0; r < 4; r++)
            red[wave * 1088 + (quad * 4 + r) * 68 + nt * 16 + lr] = acc5[nt][r];
    __syncthreads();
#pragma unroll
    for (int r = 0; r < 4; r++) {
        int M2 = quad * 4 + r, Bc = wave * 16 + lr;
        float v = red[M2 * 68 + Bc] + red[1088 + M2 * 68 + Bc] +
                  red[2176 + M2 * 68 + Bc] + red[3264 + M2 * 68 + Bc];
        float w = v * inv;
        size_t idx = (size_t)(L * 64 + O2 * 16 + M2) * 4096 + (A0 + cc * 16 + a4) * 64 + Bc;
        envSo[idx] = split2(w);
        if (wf32) env[idx] = w;
    }
}

extern "C" void kernel_launch(void* const* d_in, const int* in_sizes, int n_in,
                              void* d_out, int out_size, void* d_ws, size_t ws_size,
                              hipStream_t stream) {
    const float* state = (const float*)d_in[0];   // [8,64,16,64]
    const float* layer = (const float*)d_in[1];   // [1,8,16,16,16,16]
    const float* oper  = (const float*)d_in[2];   // [8,4,16,16,4]
    float* out = (float*)d_out;

    // F 64MiB | P 128MiB | envS0 16MiB | envB 16MiB | envS1 16MiB | packs | sv
    const size_t need = 16777216ull * 4 + 33554432ull * 4 + 3ull * 4194304ull * 4 +
                        (4ull * 1048576ull + 65536ull) * 2ull + 4096ull;
    if (ws_size < need) {
        write_diag_kernel<<<1, 64, 0, stream>>>(out, (float)ws_size);
        return;
    }
    float* F    = (float*)d_ws;                          // SCR fp32 / T2 u16
    unsigned* P = (unsigned*)(F + 16777216);             // T1 + T3 (u16)
    unsigned* envS0 = (unsigned*)(P + 33554432);         // old envA slot
    float* envB = (float*)(envS0 + 4194304);
    unsigned* envS1 = (unsigned*)(envB + 4194304);
    unsigned short* Ap2 = (unsigned short*)(envS1 + 4194304);
    unsigned short* Ap4 = Ap2 + 1048576;
    unsigned short* Sp1 = Ap4 + 1048576;
    unsigned short* Sp5 = Sp1 + 1048576;
    unsigned short* Op3 = Sp5 + 1048576;
    float* sv = (float*)(Op3 + 65536);
    float* SCR = F;
    unsigned short* T1 = (unsigned short*)P;
    unsigned short* T3 = T1 + 33554432;
    unsigned short* T2 = (unsigned short*)F;

    prep_apack<<<256, 256, 0, stream>>>(layer, Ap2, Ap4);
    prep_spack1<<<256, 256, 0, stream>>>(state, Sp1);
    prep_spack5<<<256, 256, 0, stream>>>(state, Sp5);
    prep_opack3<<<16, 256, 0, stream>>>(oper, Op3);
    prep_sv<<<4, 256, 0, stream>>>(state, sv);

    // site 0 -> envB (exact fp32), then one split into envS1
    s0_g2<<<64, 256, 0, stream>>>(state, layer, SCR);
    s0_g3<<<256, 256, 0, stream>>>(SCR, oper, SCR + 16384);
    s0_g4<<<4096, 256, 0, stream>>>(SCR + 16384, layer, SCR + 81920);
    s0_env<<<16384, 256, 0, stream>>>(SCR + 81920, state, envB);
    env_split_k<<<4096, 256, 0, stream>>>(envB, envS1);

    for (int q = 1; q < 7; q++) {
        unsigned* einS  = (q & 1) ? envS1 : envS0;
        unsigned* eoutS = (q & 1) ? envS0 : envS1;
        float scl = (float)(1u << (16 + 2 * q));   // exact power of 2
        float inv = 1.0f / scl;
        int wf32 = (q == 6) ? 1 : 0;
        for (int p = 0; p < 2; p++) {
            gemm_g1<<<2048, 256, 0, stream>>>(
                einS, Sp1 + (size_t)(q * 4 + p * 2) * 32768, T1, scl);
            gemm_g2<<<2048, 256, 0, stream>>>(
                T1, Ap2 + (size_t)q * 131072, T2);
            gemm_g3<<<8192, 256, 0, stream>>>(
                T2, Op3 + (size_t)q * 8192, T3);
            gemm_g45<<<2048, 256, 0, stream>>>(
                T3, Ap4 + (size_t)q * 131072, Sp5 + (size_t)q * 131072,
                envB, eoutS, p * 32, inv, wf32);
        }
    }

    // site 7: out = <env7 (in envB), w>
    s7_c1<<<64, 256, 0, stream>>>(state, layer, SCR);
    s7_c2<<<256, 256, 0, stream>>>(SCR, oper, SCR + 16384);
    s7_c3<<<4096, 256, 0, stream>>>(SCR + 16384, layer, SCR + 81920);
    zero_out<<<1, 64, 0, stream>>>(out);
    s7_fused<<<1024, 256, 0, stream>>>(envB, SCR + 81920, sv, out);
}

// Round 5
// 1538.083 us; speedup vs baseline: 1.6675x; 1.0661x over previous
//
#include <hip/hip_runtime.h>

// ---------------------------------------------------------------------------
// <psi|U^dag O U|psi>, NQ=8, r=64 d=16 rl=16 ro=4.
// R17 = R16 + fuse gemm_g3 into gemm_g45's prologue:
//   g45 block (cc,O2,L,a4) needs exactly the mt=O2 slice of g3 blocks
//   (L,m2=0..15,a4); g3's MFMA work partitions perfectly across g45 blocks
//   (8192x4x8 == 2048x4x32). So g45 now computes its own 32KB B panel:
//   for m2=0..15: acc3 = Op3[O2] x T2[(L,m2,a4)] (2 MFMAs, T2 depth-2
//   prefetched from L2/L3), f2h -> write into Bs via LDS at g3's exact byte
//   layout, one barrier, phase A unchanged. Bit-identical f16 bits.
//   Kills: g3 kernel (12 dispatches incl. a 20.7ms anomaly in the R16
//   profile), T3 buffer, 64MB T3 write + 34MB HBM fetch per g45.
// Everything else identical to R16.
// ---------------------------------------------------------------------------

typedef __attribute__((ext_vector_type(8))) short bf16x8;
typedef __attribute__((ext_vector_type(8))) _Float16 f16x8;
typedef __attribute__((ext_vector_type(4))) float f32x4;
typedef __attribute__((ext_vector_type(4))) unsigned short us4;

static __device__ __forceinline__ unsigned short f2bf(float x) {
    union { float f; unsigned u; } a; a.f = x;
    return (unsigned short)((a.u + 0x7FFF + ((a.u >> 16) & 1)) >> 16);
}
static __device__ __forceinline__ float bf2f(unsigned short h) {
    union { unsigned u; float f; } a; a.u = (unsigned)h << 16; return a.f;
}
static __device__ __forceinline__ unsigned split2(float x) {
    unsigned short h = f2bf(x);
    unsigned short l = f2bf(x - bf2f(h));
    return (unsigned)h | ((unsigned)l << 16);
}
static __device__ __forceinline__ unsigned short f2h_bits(float x) {
    union { _Float16 h; unsigned short u; } c; c.h = (_Float16)x; return c.u;
}
static __device__ __forceinline__ float h2f_bits(unsigned short u) {
    union { unsigned short u; _Float16 h; } c; c.u = u; return (float)c.h;
}
// async global->LDS, 16B per lane; lds base must be wave-uniform.
static __device__ __forceinline__ void gl_lds16(const unsigned short* g,
                                                unsigned short* l) {
    __builtin_amdgcn_global_load_lds(
        (const __attribute__((address_space(1))) unsigned int*)g,
        (__attribute__((address_space(3))) unsigned int*)l, 16, 0, 0);
}

__global__ void write_diag_kernel(float* out, float v) {
    if (threadIdx.x == 0 && blockIdx.x == 0) out[0] = v;
}
__global__ void zero_out(float* o) {
    if (threadIdx.x == 0 && blockIdx.x == 0) o[0] = 0.0f;
}

// ---- A-operand fragment packs -------------------------------------------
__global__ void prep_apack(const float* __restrict__ layer,
                           unsigned short* __restrict__ Ap2,
                           unsigned short* __restrict__ Ap4) {
    int idx = blockIdx.x * 256 + threadIdx.x;   // 65536
    int q = idx >> 13, k0 = (idx >> 10) & 7, mt = (idx >> 6) & 15, lane = idx & 63;
    int quad = lane >> 4, r = lane & 15;
    unsigned short h2[8], l2[8], h4[8], l4[8];
#pragma unroll
    for (int j = 0; j < 8; j++) {
        int k = k0 * 32 + quad * 8 + j;
        int m = mt * 16 + r;
        float v2 = layer[(size_t)q * 65536 +
                         (size_t)((((k >> 4) * 16 + (m >> 4)) * 16 + (k & 15)) * 16 + (m & 15))];
        float v4 = layer[(size_t)q * 65536 +
                         (size_t)((((k >> 4) * 16 + (k & 15)) * 16 + (m >> 4)) * 16 + (m & 15))];
        h2[j] = f2h_bits(v2); l2[j] = f2h_bits(v2 - h2f_bits(h2[j]));
        h4[j] = f2h_bits(v4); l4[j] = f2h_bits(v4 - h2f_bits(h4[j]));
    }
    size_t base = ((size_t)((q * 8 + k0) * 16 + mt) * 2) * 512 + lane * 8;
    *(us4*)(Ap2 + base)       = *(us4*)&h2[0];
    *(us4*)(Ap2 + base + 4)   = *(us4*)&h2[4];
    *(us4*)(Ap2 + base + 512) = *(us4*)&l2[0];
    *(us4*)(Ap2 + base + 516) = *(us4*)&l2[4];
    *(us4*)(Ap4 + base)       = *(us4*)&h4[0];
    *(us4*)(Ap4 + base + 4)   = *(us4*)&h4[4];
    *(us4*)(Ap4 + base + 512) = *(us4*)&l4[0];
    *(us4*)(Ap4 + base + 516) = *(us4*)&l4[4];
}

__global__ void prep_spack1(const float* __restrict__ state,
                            unsigned short* __restrict__ Sp1) {
    int idx = blockIdx.x * 256 + threadIdx.x;   // 65536
    int q = idx >> 13, c = (idx >> 11) & 3, k0 = (idx >> 10) & 1,
        mt = (idx >> 6) & 15, lane = idx & 63;
    int quad = lane >> 4, lr = lane & 15;
    unsigned short h[8], l[8];
#pragma unroll
    for (int j = 0; j < 8; j++) {
        int k = k0 * 32 + quad * 8 + j;
        float v = state[(size_t)q * 65536 + (size_t)(k * 16 + mt) * 64 + c * 16 + lr];
        h[j] = f2bf(v); l[j] = f2bf(v - bf2f(h[j]));
    }
    size_t base = (size_t)(q * 4 + c) * 32768 + ((size_t)(k0 * 16 + mt) * 2) * 512 + lane * 8;
    *(us4*)(Sp1 + base)       = *(us4*)&h[0];
    *(us4*)(Sp1 + base + 4)   = *(us4*)&h[4];
    *(us4*)(Sp1 + base + 512) = *(us4*)&l[0];
    *(us4*)(Sp1 + base + 516) = *(us4*)&l[4];
}

__global__ void prep_spack5(const float* __restrict__ state,
                            unsigned short* __restrict__ Sp5) {
    int idx = blockIdx.x * 256 + threadIdx.x;   // 65536
    int q = idx >> 13, k0 = (idx >> 8) & 31, mt = (idx >> 6) & 3, lane = idx & 63;
    int quad = lane >> 4, lr = lane & 15;
    unsigned short h[8], l[8];
#pragma unroll
    for (int j = 0; j < 8; j++) {
        int k = k0 * 32 + quad * 8 + j;   // k = s*64+b
        int s = k >> 6, b = k & 63;
        float v = state[(size_t)q * 65536 + (size_t)(b * 16 + s) * 64 + mt * 16 + lr];
        h[j] = f2bf(v); l[j] = f2bf(v - bf2f(h[j]));
    }
    size_t base = (size_t)q * 131072 + ((size_t)(k0 * 4 + mt) * 2) * 512 + lane * 8;
    *(us4*)(Sp5 + base)       = *(us4*)&h[0];
    *(us4*)(Sp5 + base + 4)   = *(us4*)&h[4];
    *(us4*)(Sp5 + base + 512) = *(us4*)&l[0];
    *(us4*)(Sp5 + base + 516) = *(us4*)&l[4];
}

__global__ void prep_opack3(const float* __restrict__ oper,
                            unsigned short* __restrict__ Op3) {
    int idx = blockIdx.x * 256 + threadIdx.x;   // 4096
    int q = idx >> 9, k0 = (idx >> 8) & 1, mt = (idx >> 6) & 3, lane = idx & 63;
    int quad = lane >> 4, lr = lane & 15;
    unsigned short h[8], l[8];
#pragma unroll
    for (int j = 0; j < 8; j++) {
        int k = k0 * 32 + quad * 8 + j;
        int m = mt * 16 + lr;
        float v = oper[(size_t)q * 4096 + (size_t)(k * 16 + (m & 15)) * 4 + (m >> 4)];
        h[j] = f2h_bits(v); l[j] = f2h_bits(v - h2f_bits(h[j]));
    }
    size_t base = (size_t)q * 8192 + ((size_t)(k0 * 4 + mt) * 2) * 512 + lane * 8;
    *(us4*)(Op3 + base)       = *(us4*)&h[0];
    *(us4*)(Op3 + base + 4)   = *(us4*)&h[4];
    *(us4*)(Op3 + base + 512) = *(us4*)&l[0];
    *(us4*)(Op3 + base + 516) = *(us4*)&l[4];
}

// ---- env fp32 -> packed u32 (bf16 hi | lo<<16), once after site 0 -------
__global__ void env_split_k(const float* __restrict__ env, unsigned* __restrict__ envS) {
    int t = blockIdx.x * 256 + threadIdx.x;   // 1048576 x float4
    float4 v = ((const float4*)env)[t];
    uint4 o;
    o.x = split2(v.x); o.y = split2(v.y); o.z = split2(v.z); o.w = split2(v.w);
    ((uint4*)envS)[t] = o;
}

// ---- site 0 (env0 = delta): env1 built by a cheap chain (fp32 exact) ----
__global__ void s0_g2(const float* __restrict__ state, const float* __restrict__ layer,
                      float* __restrict__ g2) {
    int t = blockIdx.x * 256 + threadIdx.x;          // 16384: [A][j][L]
    int A = t >> 8, j = (t >> 4) & 15, L = t & 15;
    float s = 0;
    for (int i = 0; i < 16; i++) s += state[i * 64 + A] * layer[(j * 16 + i) * 16 + L];
    g2[t] = s;
}
__global__ void s0_g3(const float* __restrict__ g2, const float* __restrict__ oper,
                      float* __restrict__ g3) {
    int t = blockIdx.x * 256 + threadIdx.x;          // 65536: [A][L][k][O]
    int A = t >> 10, L = (t >> 6) & 15, k = (t >> 2) & 15, O = t & 3;
    float s = 0;
    for (int j = 0; j < 16; j++) s += g2[A * 256 + j * 16 + L] * oper[(j * 16 + k) * 4 + O];
    g3[t] = s;
}
__global__ void s0_g4(const float* __restrict__ g3, const float* __restrict__ layer,
                      float* __restrict__ g4) {
    int t = blockIdx.x * 256 + threadIdx.x;          // 1048576: [A][L][O][s][M]
    int A = t >> 14, L = (t >> 10) & 15, O = (t >> 8) & 3, sp = (t >> 4) & 15, M = t & 15;
    float s = 0;
    for (int k = 0; k < 16; k++)
        s += g3[A * 1024 + L * 64 + k * 4 + O] * layer[(k * 16 + sp) * 16 + M];
    g4[t] = s;
}
__global__ void s0_env(const float* __restrict__ g4, const float* __restrict__ state,
                       float* __restrict__ env) {
    int t = blockIdx.x * 256 + threadIdx.x;          // 4194304
    int A = t >> 16, L = (t >> 12) & 15, O = (t >> 10) & 3, M = (t >> 6) & 15, B = t & 63;
    float s = 0;
    for (int sp = 0; sp < 16; sp++)
        s += g4[A * 16384 + L * 1024 + O * 256 + sp * 16 + M] * state[sp * 64 + B];
    env[(size_t)(L * 64 + O * 16 + M) * 4096 + A * 64 + B] = s;
}

// ---- site 7 chain (fp32) + fused dot ------------------------------------
__global__ void s7_c1(const float* __restrict__ state, const float* __restrict__ layer,
                      float* __restrict__ c1) {
    int t = blockIdx.x * 256 + threadIdx.x;          // 16384: [l][a][j]
    int l = t >> 10, a = (t >> 4) & 63, j = t & 15;
    float s = 0;
    for (int i = 0; i < 16; i++)
        s += state[7 * 65536 + (a * 16 + i) * 64] * layer[7 * 65536 + ((l * 16 + j) * 16 + i) * 16];
    c1[t] = s;
}
__global__ void s7_c2(const float* __restrict__ c1, const float* __restrict__ oper,
                      float* __restrict__ c2) {
    int t = blockIdx.x * 256 + threadIdx.x;          // 65536: [o][l][a][k]
    int o = t >> 14, l = (t >> 10) & 15, a = (t >> 4) & 63, k = t & 15;
    float s = 0;
    for (int j = 0; j < 16; j++)
        s += c1[l * 1024 + a * 16 + j] * oper[7 * 4096 + ((o * 16 + j) * 16 + k) * 4];
    c2[t] = s;
}
__global__ void s7_c3(const float* __restrict__ c2, const float* __restrict__ layer,
                      float* __restrict__ c3) {
    int t = blockIdx.x * 256 + threadIdx.x;          // 1048576: [m][o][l][a][s]
    int m = t >> 16, o = (t >> 14) & 3, l = (t >> 10) & 15, a = (t >> 4) & 63, sp = t & 15;
    float s = 0;
    for (int k = 0; k < 16; k++)
        s += c2[o * 16384 + l * 1024 + a * 16 + k] *
             layer[7 * 65536 + ((m * 16 + k) * 16 + sp) * 16];
    c3[t] = s;
}
__global__ void prep_sv(const float* __restrict__ state, float* __restrict__ sv) {
    int t = blockIdx.x * 256 + threadIdx.x;          // 1024: [b][sp]
    sv[t] = state[7 * 65536 + t * 64];
}
__global__ __launch_bounds__(256) void s7_fused(const float* __restrict__ env,
                                                const float* __restrict__ c3,
                                                const float* __restrict__ sv,
                                                float* __restrict__ out) {
    __shared__ float c3s[1024], svs[1024], red[256];
    int t = threadIdx.x;
    int n0 = blockIdx.x * 64;            // region=(l,o,m)
    int l = n0 >> 12, o = (n0 >> 10) & 3, m = (n0 >> 6) & 15;
    const float* c3b = c3 + m * 65536 + o * 16384 + l * 1024;   // [a][sp]
    const float* eb  = env + (size_t)blockIdx.x * 4096;         // [a][b]
    for (int i = t; i < 1024; i += 256) { c3s[i] = c3b[i]; svs[i] = sv[i]; }
    __syncthreads();
    float s = 0;
    int b = t & 63, ag = t >> 6;
#pragma unroll
    for (int g = 0; g < 16; g++) {
        int a = ag * 16 + g;
        float e = eb[a * 64 + b];
        float w = 0;
#pragma unroll
        for (int sp = 0; sp < 16; sp++) w += c3s[a * 16 + sp] * svs[b * 16 + sp];
        s += e * w;
    }
    red[t] = s; __syncthreads();
    for (int off = 128; off; off >>= 1) { if (t < off) red[t] += red[t + off]; __syncthreads(); }
    if (t == 0) atomicAdd(out, red[0]);
}

// ---- G1: envS (pre-split u32, LDS-staged) x Sp1 -> t1 f16 panels ---------
// grid 2048 = cc(2) x [l(16) o(4) m2(16)]; A operands prefetched 1 k0 ahead.
__global__ __launch_bounds__(256) void gemm_g1(const unsigned* __restrict__ envS,
                                               const unsigned short* __restrict__ Sp1,
                                               unsigned short* __restrict__ t1,
                                               float scale) {
    __shared__ unsigned Bt[32 * 65];
    const int tid = threadIdx.x, lane = tid & 63, wave = tid >> 6;
    const int quad = lane >> 4, lr = lane & 15;
    const int cc = blockIdx.x >> 10, rid = blockIdx.x & 1023;
    const int l = rid >> 6, o = (rid >> 4) & 3, m2 = rid & 15;

    f32x4 acc[4][4];
#pragma unroll
    for (int i = 0; i < 4; i++)
#pragma unroll
        for (int j = 0; j < 4; j++)
#pragma unroll
            for (int r = 0; r < 4; r++) acc[i][j][r] = 0.0f;

    const unsigned* Bv = envS + (size_t)rid * 4096;
    const unsigned short* Sp1c = Sp1 + (size_t)cc * 32768;
    uint4 ur[2];
    auto load_tile = [&](int k0) {
        const uint4* src = (const uint4*)(Bv + k0 * 2048);
        ur[0] = src[tid];
        ur[1] = src[256 + tid];
    };
    auto store_tile = [&]() {
#pragma unroll
        for (int v = 0; v < 2; v++) {
            int e = v * 256 + tid;
            unsigned* p = &Bt[(e >> 4) * 65 + (e & 15) * 4];
            p[0] = ur[v].x; p[1] = ur[v].y; p[2] = ur[v].z; p[3] = ur[v].w;
        }
    };

    bf16x8 ahb[2][4], alb[2][4];
    auto loadA = [&](int k0, int buf) {
#pragma unroll
        for (int mt = 0; mt < 4; mt++) {
            int gmt = wave * 4 + mt;
            const unsigned short* ap = Sp1c + ((size_t)(k0 * 16 + gmt) * 2) * 512 + lane * 8;
            ahb[buf][mt] = *(const bf16x8*)ap;
            alb[buf][mt] = *(const bf16x8*)(ap + 512);
        }
    };

    load_tile(0);
    loadA(0, 0);
    store_tile();
#pragma unroll
    for (int k0 = 0; k0 < 2; k0++) {
        __syncthreads();
        if (k0 + 1 < 2) { load_tile(k0 + 1); loadA(k0 + 1, 1); }
#pragma unroll
        for (int nt = 0; nt < 4; nt++) {
            int nl = nt * 16 + lr;
            bf16x8 bh, bl;
#pragma unroll
            for (int j = 0; j < 8; j++) {
                unsigned u = Bt[(quad * 8 + j) * 65 + nl];
                bh[j] = (short)(u & 0xffffu);
                bl[j] = (short)(u >> 16);
            }
#pragma unroll
            for (int mt = 0; mt < 4; mt++) {
                acc[mt][nt] = __builtin_amdgcn_mfma_f32_16x16x32_bf16(ahb[k0][mt], bh, acc[mt][nt], 0, 0, 0);
                acc[mt][nt] = __builtin_amdgcn_mfma_f32_16x16x32_bf16(ahb[k0][mt], bl, acc[mt][nt], 0, 0, 0);
                acc[mt][nt] = __builtin_amdgcn_mfma_f32_16x16x32_bf16(alb[k0][mt], bh, acc[mt][nt], 0, 0, 0);
            }
        }
        __syncthreads();
        if (k0 + 1 < 2) store_tile();
    }

#pragma unroll
    for (int nt = 0; nt < 4; nt++) {
        int b = nt * 16 + lr;
#pragma unroll
        for (int r = 0; r < 4; r++) {
            int a4 = quad * 4 + r;
            us4 w;
#pragma unroll
            for (int mt = 0; mt < 4; mt++) w[mt] = f2h_bits(acc[mt][nt][r] * scale);
            size_t addr = (size_t)cc * 16777216 +
                          (size_t)(o * 256 + m2 * 16 + a4) * 16384 +
                          (size_t)(l * 2 + (wave >> 1)) * 512 + b * 8 + (wave & 1) * 4;
            *(us4*)(t1 + addr) = w;
        }
    }
}

// ---- G2: B panel LDS-staged via global_load_lds; A depth-2 prefetch ------
// grid 2048 = cc(2) x [o(4) m2(16) a4(16)]
__global__ __launch_bounds__(256) void gemm_g2(const unsigned short* __restrict__ Bp,
                                               const unsigned short* __restrict__ Ap,
                                               unsigned short* __restrict__ Co) {
    __shared__ __align__(16) unsigned short Bs[16384];   // 32KB panel
    const int tid = threadIdx.x, lane = tid & 63, wave = tid >> 6;
    const int quad = lane >> 4, lr = lane & 15;
    const int cc = blockIdx.x >> 10, rid = blockIdx.x & 1023;
    const int o = rid >> 8, m2 = (rid >> 4) & 15, a4 = rid & 15;
    const unsigned short* pb = Bp + (size_t)blockIdx.x * 16384;
    unsigned short* Cb = Co + (size_t)cc * 16777216;

#pragma unroll
    for (int i = 0; i < 8; i++)
        gl_lds16(pb + i * 2048 + tid * 8, Bs + i * 2048 + wave * 512);

    f32x4 acc[4][4];
#pragma unroll
    for (int i = 0; i < 4; i++)
#pragma unroll
        for (int j = 0; j < 4; j++)
#pragma unroll
            for (int r = 0; r < 4; r++) acc[i][j][r] = 0.0f;

    f16x8 ah[3][4];
    auto loadA = [&](int k0, int buf) {
#pragma unroll
        for (int mt = 0; mt < 4; mt++) {
            int gmt = wave * 4 + mt;
            ah[buf][mt] = *(const f16x8*)(Ap + ((size_t)(k0 * 16 + gmt) * 2) * 512 + lane * 8);
        }
    };
    loadA(0, 0);
    loadA(1, 1);

    asm volatile("s_waitcnt vmcnt(0)" ::: "memory");
    __syncthreads();

#pragma unroll
    for (int k0 = 0; k0 < 8; k0++) {
        if (k0 + 2 < 8) loadA(k0 + 2, (k0 + 2) % 3);
        f16x8 bfr[4];
#pragma unroll
        for (int nt = 0; nt < 4; nt++)
            bfr[nt] = *(const f16x8*)(Bs + (k0 * 4 + quad) * 512 + (nt * 16 + lr) * 8);
#pragma unroll
        for (int nt = 0; nt < 4; nt++)
#pragma unroll
            for (int mt = 0; mt < 4; mt++)
                acc[mt][nt] = __builtin_amdgcn_mfma_f32_16x16x32_f16(
                    ah[k0 % 3][mt], bfr[nt], acc[mt][nt], 0, 0, 0);
    }

#pragma unroll
    for (int nt = 0; nt < 4; nt++) {
        int b = nt * 16 + lr;
#pragma unroll
        for (int r = 0; r < 4; r++) {
            int L = quad * 4 + r;
            us4 w;
#pragma unroll
            for (int mt = 0; mt < 4; mt++) w[mt] = f2h_bits(acc[mt][nt][r]);
            size_t addr = (size_t)(L * 256 + m2 * 16 + a4) * 4096 +
                          (size_t)(o * 2 + (wave >> 1)) * 512 + b * 8 + (wave & 1) * 4;
            *(us4*)(Cb + addr) = w;
        }
    }
}

// ---- fused G3+G4+G5: B panel computed in-kernel from T2 x Op3 ------------
// grid 2048 = cc(2) x [O2(4) L(16) a4(16)]; A0 = pair*32, A = A0+cc*16+a4
// Prologue: for m2=0..15: acc3 = Op3[mt=O2] x T2[(L,m2,a4)] (2 MFMAs),
//   f2h -> Bs at g3's exact byte layout (bit-identical to R16's T3 panel).
// Writes split-u32 env (envSo) always; fp32 env only when wf32 (q==6).
__global__ __launch_bounds__(256) void gemm_g45(const unsigned short* __restrict__ T2,
                                                const unsigned short* __restrict__ Op3q,
                                                const unsigned short* __restrict__ Ap4,
                                                const unsigned short* __restrict__ Sp5,
                                                float* __restrict__ env,
                                                unsigned* __restrict__ envSo,
                                                int A0, float inv, int wf32) {
    __shared__ __align__(16) unsigned short Bs[16384];   // 32KB B panel
    __shared__ unsigned SL[4 * 16 * 68];                 // slab / reduce buffer
    const int tid = threadIdx.x, lane = tid & 63, wave = tid >> 6;
    const int quad = lane >> 4, lr = lane & 15;
    const int cc = blockIdx.x >> 10, rid = blockIdx.x & 1023;
    const int O2 = rid >> 8, L = (rid >> 4) & 15, a4 = rid & 15;
    const unsigned short* T2c = T2 + (size_t)cc * 16777216;
    const int b8 = (wave * 16 + lr) * 8;   // b*8, b = wave*16+lr (g3 layout)

    // phase-A A-panel prefetch rides alongside the prologue
    f16x8 ah[3][4];
    auto loadA = [&](int k0, int buf) {
#pragma unroll
        for (int mt = 0; mt < 4; mt++) {
            int gmt = wave * 4 + mt;
            ah[buf][mt] = *(const f16x8*)(Ap4 + ((size_t)(k0 * 16 + gmt) * 2) * 512 + lane * 8);
        }
    };
    loadA(0, 0);
    loadA(1, 1);

    // ---- fused G3 prologue: build Bs = Op3[O2] x T2[(L,m2,a4)] -----------
    {
        f16x8 oh0 = *(const f16x8*)(Op3q + (size_t)(O2 * 2) * 512 + lane * 8);
        f16x8 oh1 = *(const f16x8*)(Op3q + (size_t)((4 + O2) * 2) * 512 + lane * 8);
        f16x8 tb[2][2];
        auto loadT2 = [&](int m2, int buf) {
            const unsigned short* pp = T2c + (size_t)(L * 256 + m2 * 16 + a4) * 4096;
            tb[buf][0] = *(const f16x8*)(pp + (quad << 9) + b8);
            tb[buf][1] = *(const f16x8*)(pp + ((4 + quad) << 9) + b8);
        };
        loadT2(0, 0);
#pragma unroll
        for (int m2 = 0; m2 < 16; m2++) {
            if (m2 + 1 < 16) loadT2(m2 + 1, (m2 + 1) & 1);
            f32x4 a3;
            a3[0] = a3[1] = a3[2] = a3[3] = 0.0f;
            a3 = __builtin_amdgcn_mfma_f32_16x16x32_f16(oh0, tb[m2 & 1][0], a3, 0, 0, 0);
            a3 = __builtin_amdgcn_mfma_f32_16x16x32_f16(oh1, tb[m2 & 1][1], a3, 0, 0, 0);
            us4 w;
#pragma unroll
            for (int r = 0; r < 4; r++) w[r] = f2h_bits(a3[r]);
            *(us4*)(Bs + (m2 * 2 + (quad >> 1)) * 512 + b8 + (quad & 1) * 4) = w;
        }
    }
    __syncthreads();

    f32x4 acc[4][4];
#pragma unroll
    for (int i = 0; i < 4; i++)
#pragma unroll
        for (int j = 0; j < 4; j++)
#pragma unroll
            for (int r = 0; r < 4; r++) acc[i][j][r] = 0.0f;

#pragma unroll
    for (int k0 = 0; k0 < 8; k0++) {
        if (k0 + 2 < 8) loadA(k0 + 2, (k0 + 2) % 3);
        f16x8 bfr[4];
#pragma unroll
        for (int nt = 0; nt < 4; nt++)
            bfr[nt] = *(const f16x8*)(Bs + (k0 * 4 + quad) * 512 + (nt * 16 + lr) * 8);
#pragma unroll
        for (int nt = 0; nt < 4; nt++)
#pragma unroll
            for (int mt = 0; mt < 4; mt++)
                acc[mt][nt] = __builtin_amdgcn_mfma_f32_16x16x32_f16(
                    ah[k0 % 3][mt], bfr[nt], acc[mt][nt], 0, 0, 0);
    }

    // phase B: per-wave k-quarter (s = 4*wave..4*wave+3), barrier-free.
    unsigned* myslab = SL + wave * (16 * 68);
    f32x4 acc5[4];
#pragma unroll
    for (int nt = 0; nt < 4; nt++)
#pragma unroll
        for (int r = 0; r < 4; r++) acc5[nt][r] = 0.0f;

    // Sp5 depth-1 pipeline: step = mtp*2+h, buffers by step parity.
    bf16x8 s5h[2][4], s5l[2][4];
    auto loadS5 = [&](int step, int buf) {
        int kg = (wave * 4 + (step >> 1)) * 2 + (step & 1);
#pragma unroll
        for (int nt = 0; nt < 4; nt++) {
            const unsigned short* bp = Sp5 + ((size_t)(kg * 4 + nt) * 2) * 512 + lane * 8;
            s5h[buf][nt] = *(const bf16x8*)bp;
            s5l[buf][nt] = *(const bf16x8*)(bp + 512);
        }
    };
    loadS5(0, 0);

#pragma unroll
    for (int mtp = 0; mtp < 4; mtp++) {
        // deposit own slab [M2=16][b=64 pad 68] (u32 split-pair)
#pragma unroll
        for (int nt = 0; nt < 4; nt++)
#pragma unroll
            for (int r = 0; r < 4; r++)
                myslab[(quad * 4 + r) * 68 + nt * 16 + lr] = split2(acc[mtp][nt][r]);
        // same-wave cross-lane LDS dependency: drain LDS pipe (vmcnt loads
        // from loadS5 stay in flight - lgkmcnt does not wait on them)
        asm volatile("s_waitcnt lgkmcnt(0)" ::: "memory");
#pragma unroll
        for (int h = 0; h < 2; h++) {
            const int step = mtp * 2 + h;
            const unsigned* sp = &myslab[lr * 68 + h * 32 + quad * 8];
            uint4 u0 = *(const uint4*)sp;
            uint4 u1 = *(const uint4*)(sp + 4);
            bf16x8 th, tl;
            th[0] = (short)(u0.x & 0xffff); tl[0] = (short)(u0.x >> 16);
            th[1] = (short)(u0.y & 0xffff); tl[1] = (short)(u0.y >> 16);
            th[2] = (short)(u0.z & 0xffff); tl[2] = (short)(u0.z >> 16);
            th[3] = (short)(u0.w & 0xffff); tl[3] = (short)(u0.w >> 16);
            th[4] = (short)(u1.x & 0xffff); tl[4] = (short)(u1.x >> 16);
            th[5] = (short)(u1.y & 0xffff); tl[5] = (short)(u1.y >> 16);
            th[6] = (short)(u1.z & 0xffff); tl[6] = (short)(u1.z >> 16);
            th[7] = (short)(u1.w & 0xffff); tl[7] = (short)(u1.w >> 16);
            if (step + 1 < 8) loadS5(step + 1, (step + 1) & 1);
#pragma unroll
            for (int nt = 0; nt < 4; nt++) {
                acc5[nt] = __builtin_amdgcn_mfma_f32_16x16x32_bf16(th, s5h[step & 1][nt], acc5[nt], 0, 0, 0);
                acc5[nt] = __builtin_amdgcn_mfma_f32_16x16x32_bf16(th, s5l[step & 1][nt], acc5[nt], 0, 0, 0);
                acc5[nt] = __builtin_amdgcn_mfma_f32_16x16x32_bf16(tl, s5h[step & 1][nt], acc5[nt], 0, 0, 0);
            }
        }
    }

    // cross-wave reduce: one barrier, float view of SL
    __syncthreads();
    float* red = (float*)SL;
#pragma unroll
    for (int nt = 0; nt < 4; nt++)
#pragma unroll
        for (int r = 0; r < 4; r++)
            red[wave * 1088 + (quad * 4 + r) * 68 + nt * 16 + lr] = acc5[nt][r];
    __syncthreads();
#pragma unroll
    for (int r = 0; r < 4; r++) {
        int M2 = quad * 4 + r, Bc = wave * 16 + lr;
        float v = red[M2 * 68 + Bc] + red[1088 + M2 * 68 + Bc] +
                  red[2176 + M2 * 68 + Bc] + red[3264 + M2 * 68 + Bc];
        float w = v * inv;
        size_t idx = (size_t)(L * 64 + O2 * 16 + M2) * 4096 + (A0 + cc * 16 + a4) * 64 + Bc;
        envSo[idx] = split2(w);
        if (wf32) env[idx] = w;
    }
}

extern "C" void kernel_launch(void* const* d_in, const int* in_sizes, int n_in,
                              void* d_out, int out_size, void* d_ws, size_t ws_size,
                              hipStream_t stream) {
    const float* state = (const float*)d_in[0];   // [8,64,16,64]
    const float* layer = (const float*)d_in[1];   // [1,8,16,16,16,16]
    const float* oper  = (const float*)d_in[2];   // [8,4,16,16,4]
    float* out = (float*)d_out;

    // F 64MiB | P 128MiB | envS0 16MiB | envB 16MiB | envS1 16MiB | packs | sv
    const size_t need = 16777216ull * 4 + 33554432ull * 4 + 3ull * 4194304ull * 4 +
                        (4ull * 1048576ull + 65536ull) * 2ull + 4096ull;
    if (ws_size < need) {
        write_diag_kernel<<<1, 64, 0, stream>>>(out, (float)ws_size);
        return;
    }
    float* F    = (float*)d_ws;                          // SCR fp32 / T2 u16
    unsigned* P = (unsigned*)(F + 16777216);             // T1 (u16)
    unsigned* envS0 = (unsigned*)(P + 33554432);
    float* envB = (float*)(envS0 + 4194304);
    unsigned* envS1 = (unsigned*)(envB + 4194304);
    unsigned short* Ap2 = (unsigned short*)(envS1 + 4194304);
    unsigned short* Ap4 = Ap2 + 1048576;
    unsigned short* Sp1 = Ap4 + 1048576;
    unsigned short* Sp5 = Sp1 + 1048576;
    unsigned short* Op3 = Sp5 + 1048576;
    float* sv = (float*)(Op3 + 65536);
    float* SCR = F;
    unsigned short* T1 = (unsigned short*)P;
    unsigned short* T2 = (unsigned short*)F;

    prep_apack<<<256, 256, 0, stream>>>(layer, Ap2, Ap4);
    prep_spack1<<<256, 256, 0, stream>>>(state, Sp1);
    prep_spack5<<<256, 256, 0, stream>>>(state, Sp5);
    prep_opack3<<<16, 256, 0, stream>>>(oper, Op3);
    prep_sv<<<4, 256, 0, stream>>>(state, sv);

    // site 0 -> envB (exact fp32), then one split into envS1
    s0_g2<<<64, 256, 0, stream>>>(state, layer, SCR);
    s0_g3<<<256, 256, 0, stream>>>(SCR, oper, SCR + 16384);
    s0_g4<<<4096, 256, 0, stream>>>(SCR + 16384, layer, SCR + 81920);
    s0_env<<<16384, 256, 0, stream>>>(SCR + 81920, state, envB);
    env_split_k<<<4096, 256, 0, stream>>>(envB, envS1);

    for (int q = 1; q < 7; q++) {
        unsigned* einS  = (q & 1) ? envS1 : envS0;
        unsigned* eoutS = (q & 1) ? envS0 : envS1;
        float scl = (float)(1u << (16 + 2 * q));   // exact power of 2
        float inv = 1.0f / scl;
        int wf32 = (q == 6) ? 1 : 0;
        for (int p = 0; p < 2; p++) {
            gemm_g1<<<2048, 256, 0, stream>>>(
                einS, Sp1 + (size_t)(q * 4 + p * 2) * 32768, T1, scl);
            gemm_g2<<<2048, 256, 0, stream>>>(
                T1, Ap2 + (size_t)q * 131072, T2);
            gemm_g45<<<2048, 256, 0, stream>>>(
                T2, Op3 + (size_t)q * 8192, Ap4 + (size_t)q * 131072,
                Sp5 + (size_t)q * 131072, envB, eoutS, p * 32, inv, wf32);
        }
    }

    // site 7: out = <env7 (in envB), w>
    s7_c1<<<64, 256, 0, stream>>>(state, layer, SCR);
    s7_c2<<<256, 256, 0, stream>>>(SCR, oper, SCR + 16384);
    s7_c3<<<4096, 256, 0, stream>>>(SCR + 16384, layer, SCR + 81920);
    zero_out<<<1, 64, 0, stream>>>(out);
    s7_fused<<<1024, 256, 0, stream>>>(envB, SCR + 81920, sv, out);
}

// Round 6
// 1443.760 us; speedup vs baseline: 1.7764x; 1.0653x over previous
//
#include <hip/hip_runtime.h>

// ---------------------------------------------------------------------------
// <psi|U^dag O U|psi>, NQ=8, r=64 d=16 rl=16 ro=4.
// R18 = R17 + g45 T2-locality fix (g45 only; bit-identical output):
//  (a) XCD-aware grid reorder: rid = g*32 + O2*8 + low, panel=(L,a4)=g*8+low.
//      The 4 blocks sharing one 128KB T2 panel (O2=0..3) are now 8 apart in
//      dispatch index -> same XCD (stride 8 ≡ 0 mod 8) AND temporally
//      adjacent. Per-XCD live T2 footprint 32->16 panels (2MB <= 4MB L2):
//      the 3 panel re-reads become L2 hits instead of L3/HBM misses.
//      (R17 had O2 at stride 256: same XCD but ~256 blocks apart -> 4MB
//      footprint, L2 thrash, FETCH 82MB and ~900cy loads in the prologue.)
//  (b) prologue T2 prefetch depth 1->2 (tb[3][2] ring, mirrors ah[3]).
// Everything else identical to R17.
// ---------------------------------------------------------------------------

typedef __attribute__((ext_vector_type(8))) short bf16x8;
typedef __attribute__((ext_vector_type(8))) _Float16 f16x8;
typedef __attribute__((ext_vector_type(4))) float f32x4;
typedef __attribute__((ext_vector_type(4))) unsigned short us4;

static __device__ __forceinline__ unsigned short f2bf(float x) {
    union { float f; unsigned u; } a; a.f = x;
    return (unsigned short)((a.u + 0x7FFF + ((a.u >> 16) & 1)) >> 16);
}
static __device__ __forceinline__ float bf2f(unsigned short h) {
    union { unsigned u; float f; } a; a.u = (unsigned)h << 16; return a.f;
}
static __device__ __forceinline__ unsigned split2(float x) {
    unsigned short h = f2bf(x);
    unsigned short l = f2bf(x - bf2f(h));
    return (unsigned)h | ((unsigned)l << 16);
}
static __device__ __forceinline__ unsigned short f2h_bits(float x) {
    union { _Float16 h; unsigned short u; } c; c.h = (_Float16)x; return c.u;
}
static __device__ __forceinline__ float h2f_bits(unsigned short u) {
    union { unsigned short u; _Float16 h; } c; c.u = u; return (float)c.h;
}
// async global->LDS, 16B per lane; lds base must be wave-uniform.
static __device__ __forceinline__ void gl_lds16(const unsigned short* g,
                                                unsigned short* l) {
    __builtin_amdgcn_global_load_lds(
        (const __attribute__((address_space(1))) unsigned int*)g,
        (__attribute__((address_space(3))) unsigned int*)l, 16, 0, 0);
}

__global__ void write_diag_kernel(float* out, float v) {
    if (threadIdx.x == 0 && blockIdx.x == 0) out[0] = v;
}
__global__ void zero_out(float* o) {
    if (threadIdx.x == 0 && blockIdx.x == 0) o[0] = 0.0f;
}

// ---- A-operand fragment packs -------------------------------------------
__global__ void prep_apack(const float* __restrict__ layer,
                           unsigned short* __restrict__ Ap2,
                           unsigned short* __restrict__ Ap4) {
    int idx = blockIdx.x * 256 + threadIdx.x;   // 65536
    int q = idx >> 13, k0 = (idx >> 10) & 7, mt = (idx >> 6) & 15, lane = idx & 63;
    int quad = lane >> 4, r = lane & 15;
    unsigned short h2[8], l2[8], h4[8], l4[8];
#pragma unroll
    for (int j = 0; j < 8; j++) {
        int k = k0 * 32 + quad * 8 + j;
        int m = mt * 16 + r;
        float v2 = layer[(size_t)q * 65536 +
                         (size_t)((((k >> 4) * 16 + (m >> 4)) * 16 + (k & 15)) * 16 + (m & 15))];
        float v4 = layer[(size_t)q * 65536 +
                         (size_t)((((k >> 4) * 16 + (k & 15)) * 16 + (m >> 4)) * 16 + (m & 15))];
        h2[j] = f2h_bits(v2); l2[j] = f2h_bits(v2 - h2f_bits(h2[j]));
        h4[j] = f2h_bits(v4); l4[j] = f2h_bits(v4 - h2f_bits(h4[j]));
    }
    size_t base = ((size_t)((q * 8 + k0) * 16 + mt) * 2) * 512 + lane * 8;
    *(us4*)(Ap2 + base)       = *(us4*)&h2[0];
    *(us4*)(Ap2 + base + 4)   = *(us4*)&h2[4];
    *(us4*)(Ap2 + base + 512) = *(us4*)&l2[0];
    *(us4*)(Ap2 + base + 516) = *(us4*)&l2[4];
    *(us4*)(Ap4 + base)       = *(us4*)&h4[0];
    *(us4*)(Ap4 + base + 4)   = *(us4*)&h4[4];
    *(us4*)(Ap4 + base + 512) = *(us4*)&l4[0];
    *(us4*)(Ap4 + base + 516) = *(us4*)&l4[4];
}

__global__ void prep_spack1(const float* __restrict__ state,
                            unsigned short* __restrict__ Sp1) {
    int idx = blockIdx.x * 256 + threadIdx.x;   // 65536
    int q = idx >> 13, c = (idx >> 11) & 3, k0 = (idx >> 10) & 1,
        mt = (idx >> 6) & 15, lane = idx & 63;
    int quad = lane >> 4, lr = lane & 15;
    unsigned short h[8], l[8];
#pragma unroll
    for (int j = 0; j < 8; j++) {
        int k = k0 * 32 + quad * 8 + j;
        float v = state[(size_t)q * 65536 + (size_t)(k * 16 + mt) * 64 + c * 16 + lr];
        h[j] = f2bf(v); l[j] = f2bf(v - bf2f(h[j]));
    }
    size_t base = (size_t)(q * 4 + c) * 32768 + ((size_t)(k0 * 16 + mt) * 2) * 512 + lane * 8;
    *(us4*)(Sp1 + base)       = *(us4*)&h[0];
    *(us4*)(Sp1 + base + 4)   = *(us4*)&h[4];
    *(us4*)(Sp1 + base + 512) = *(us4*)&l[0];
    *(us4*)(Sp1 + base + 516) = *(us4*)&l[4];
}

__global__ void prep_spack5(const float* __restrict__ state,
                            unsigned short* __restrict__ Sp5) {
    int idx = blockIdx.x * 256 + threadIdx.x;   // 65536
    int q = idx >> 13, k0 = (idx >> 8) & 31, mt = (idx >> 6) & 3, lane = idx & 63;
    int quad = lane >> 4, lr = lane & 15;
    unsigned short h[8], l[8];
#pragma unroll
    for (int j = 0; j < 8; j++) {
        int k = k0 * 32 + quad * 8 + j;   // k = s*64+b
        int s = k >> 6, b = k & 63;
        float v = state[(size_t)q * 65536 + (size_t)(b * 16 + s) * 64 + mt * 16 + lr];
        h[j] = f2bf(v); l[j] = f2bf(v - bf2f(h[j]));
    }
    size_t base = (size_t)q * 131072 + ((size_t)(k0 * 4 + mt) * 2) * 512 + lane * 8;
    *(us4*)(Sp5 + base)       = *(us4*)&h[0];
    *(us4*)(Sp5 + base + 4)   = *(us4*)&h[4];
    *(us4*)(Sp5 + base + 512) = *(us4*)&l[0];
    *(us4*)(Sp5 + base + 516) = *(us4*)&l[4];
}

__global__ void prep_opack3(const float* __restrict__ oper,
                            unsigned short* __restrict__ Op3) {
    int idx = blockIdx.x * 256 + threadIdx.x;   // 4096
    int q = idx >> 9, k0 = (idx >> 8) & 1, mt = (idx >> 6) & 3, lane = idx & 63;
    int quad = lane >> 4, lr = lane & 15;
    unsigned short h[8], l[8];
#pragma unroll
    for (int j = 0; j < 8; j++) {
        int k = k0 * 32 + quad * 8 + j;
        int m = mt * 16 + lr;
        float v = oper[(size_t)q * 4096 + (size_t)(k * 16 + (m & 15)) * 4 + (m >> 4)];
        h[j] = f2h_bits(v); l[j] = f2h_bits(v - h2f_bits(h[j]));
    }
    size_t base = (size_t)q * 8192 + ((size_t)(k0 * 4 + mt) * 2) * 512 + lane * 8;
    *(us4*)(Op3 + base)       = *(us4*)&h[0];
    *(us4*)(Op3 + base + 4)   = *(us4*)&h[4];
    *(us4*)(Op3 + base + 512) = *(us4*)&l[0];
    *(us4*)(Op3 + base + 516) = *(us4*)&l[4];
}

// ---- env fp32 -> packed u32 (bf16 hi | lo<<16), once after site 0 -------
__global__ void env_split_k(const float* __restrict__ env, unsigned* __restrict__ envS) {
    int t = blockIdx.x * 256 + threadIdx.x;   // 1048576 x float4
    float4 v = ((const float4*)env)[t];
    uint4 o;
    o.x = split2(v.x); o.y = split2(v.y); o.z = split2(v.z); o.w = split2(v.w);
    ((uint4*)envS)[t] = o;
}

// ---- site 0 (env0 = delta): env1 built by a cheap chain (fp32 exact) ----
__global__ void s0_g2(const float* __restrict__ state, const float* __restrict__ layer,
                      float* __restrict__ g2) {
    int t = blockIdx.x * 256 + threadIdx.x;          // 16384: [A][j][L]
    int A = t >> 8, j = (t >> 4) & 15, L = t & 15;
    float s = 0;
    for (int i = 0; i < 16; i++) s += state[i * 64 + A] * layer[(j * 16 + i) * 16 + L];
    g2[t] = s;
}
__global__ void s0_g3(const float* __restrict__ g2, const float* __restrict__ oper,
                      float* __restrict__ g3) {
    int t = blockIdx.x * 256 + threadIdx.x;          // 65536: [A][L][k][O]
    int A = t >> 10, L = (t >> 6) & 15, k = (t >> 2) & 15, O = t & 3;
    float s = 0;
    for (int j = 0; j < 16; j++) s += g2[A * 256 + j * 16 + L] * oper[(j * 16 + k) * 4 + O];
    g3[t] = s;
}
__global__ void s0_g4(const float* __restrict__ g3, const float* __restrict__ layer,
                      float* __restrict__ g4) {
    int t = blockIdx.x * 256 + threadIdx.x;          // 1048576: [A][L][O][s][M]
    int A = t >> 14, L = (t >> 10) & 15, O = (t >> 8) & 3, sp = (t >> 4) & 15, M = t & 15;
    float s = 0;
    for (int k = 0; k < 16; k++)
        s += g3[A * 1024 + L * 64 + k * 4 + O] * layer[(k * 16 + sp) * 16 + M];
    g4[t] = s;
}
__global__ void s0_env(const float* __restrict__ g4, const float* __restrict__ state,
                       float* __restrict__ env) {
    int t = blockIdx.x * 256 + threadIdx.x;          // 4194304
    int A = t >> 16, L = (t >> 12) & 15, O = (t >> 10) & 3, M = (t >> 6) & 15, B = t & 63;
    float s = 0;
    for (int sp = 0; sp < 16; sp++)
        s += g4[A * 16384 + L * 1024 + O * 256 + sp * 16 + M] * state[sp * 64 + B];
    env[(size_t)(L * 64 + O * 16 + M) * 4096 + A * 64 + B] = s;
}

// ---- site 7 chain (fp32) + fused dot ------------------------------------
__global__ void s7_c1(const float* __restrict__ state, const float* __restrict__ layer,
                      float* __restrict__ c1) {
    int t = blockIdx.x * 256 + threadIdx.x;          // 16384: [l][a][j]
    int l = t >> 10, a = (t >> 4) & 63, j = t & 15;
    float s = 0;
    for (int i = 0; i < 16; i++)
        s += state[7 * 65536 + (a * 16 + i) * 64] * layer[7 * 65536 + ((l * 16 + j) * 16 + i) * 16];
    c1[t] = s;
}
__global__ void s7_c2(const float* __restrict__ c1, const float* __restrict__ oper,
                      float* __restrict__ c2) {
    int t = blockIdx.x * 256 + threadIdx.x;          // 65536: [o][l][a][k]
    int o = t >> 14, l = (t >> 10) & 15, a = (t >> 4) & 63, k = t & 15;
    float s = 0;
    for (int j = 0; j < 16; j++)
        s += c1[l * 1024 + a * 16 + j] * oper[7 * 4096 + ((o * 16 + j) * 16 + k) * 4];
    c2[t] = s;
}
__global__ void s7_c3(const float* __restrict__ c2, const float* __restrict__ layer,
                      float* __restrict__ c3) {
    int t = blockIdx.x * 256 + threadIdx.x;          // 1048576: [m][o][l][a][s]
    int m = t >> 16, o = (t >> 14) & 3, l = (t >> 10) & 15, a = (t >> 4) & 63, sp = t & 15;
    float s = 0;
    for (int k = 0; k < 16; k++)
        s += c2[o * 16384 + l * 1024 + a * 16 + k] *
             layer[7 * 65536 + ((m * 16 + k) * 16 + sp) * 16];
    c3[t] = s;
}
__global__ void prep_sv(const float* __restrict__ state, float* __restrict__ sv) {
    int t = blockIdx.x * 256 + threadIdx.x;          // 1024: [b][sp]
    sv[t] = state[7 * 65536 + t * 64];
}
__global__ __launch_bounds__(256) void s7_fused(const float* __restrict__ env,
                                                const float* __restrict__ c3,
                                                const float* __restrict__ sv,
                                                float* __restrict__ out) {
    __shared__ float c3s[1024], svs[1024], red[256];
    int t = threadIdx.x;
    int n0 = blockIdx.x * 64;            // region=(l,o,m)
    int l = n0 >> 12, o = (n0 >> 10) & 3, m = (n0 >> 6) & 15;
    const float* c3b = c3 + m * 65536 + o * 16384 + l * 1024;   // [a][sp]
    const float* eb  = env + (size_t)blockIdx.x * 4096;         // [a][b]
    for (int i = t; i < 1024; i += 256) { c3s[i] = c3b[i]; svs[i] = sv[i]; }
    __syncthreads();
    float s = 0;
    int b = t & 63, ag = t >> 6;
#pragma unroll
    for (int g = 0; g < 16; g++) {
        int a = ag * 16 + g;
        float e = eb[a * 64 + b];
        float w = 0;
#pragma unroll
        for (int sp = 0; sp < 16; sp++) w += c3s[a * 16 + sp] * svs[b * 16 + sp];
        s += e * w;
    }
    red[t] = s; __syncthreads();
    for (int off = 128; off; off >>= 1) { if (t < off) red[t] += red[t + off]; __syncthreads(); }
    if (t == 0) atomicAdd(out, red[0]);
}

// ---- G1: envS (pre-split u32, LDS-staged) x Sp1 -> t1 f16 panels ---------
// grid 2048 = cc(2) x [l(16) o(4) m2(16)]; A operands prefetched 1 k0 ahead.
__global__ __launch_bounds__(256) void gemm_g1(const unsigned* __restrict__ envS,
                                               const unsigned short* __restrict__ Sp1,
                                               unsigned short* __restrict__ t1,
                                               float scale) {
    __shared__ unsigned Bt[32 * 65];
    const int tid = threadIdx.x, lane = tid & 63, wave = tid >> 6;
    const int quad = lane >> 4, lr = lane & 15;
    const int cc = blockIdx.x >> 10, rid = blockIdx.x & 1023;
    const int l = rid >> 6, o = (rid >> 4) & 3, m2 = rid & 15;

    f32x4 acc[4][4];
#pragma unroll
    for (int i = 0; i < 4; i++)
#pragma unroll
        for (int j = 0; j < 4; j++)
#pragma unroll
            for (int r = 0; r < 4; r++) acc[i][j][r] = 0.0f;

    const unsigned* Bv = envS + (size_t)rid * 4096;
    const unsigned short* Sp1c = Sp1 + (size_t)cc * 32768;
    uint4 ur[2];
    auto load_tile = [&](int k0) {
        const uint4* src = (const uint4*)(Bv + k0 * 2048);
        ur[0] = src[tid];
        ur[1] = src[256 + tid];
    };
    auto store_tile = [&]() {
#pragma unroll
        for (int v = 0; v < 2; v++) {
            int e = v * 256 + tid;
            unsigned* p = &Bt[(e >> 4) * 65 + (e & 15) * 4];
            p[0] = ur[v].x; p[1] = ur[v].y; p[2] = ur[v].z; p[3] = ur[v].w;
        }
    };

    bf16x8 ahb[2][4], alb[2][4];
    auto loadA = [&](int k0, int buf) {
#pragma unroll
        for (int mt = 0; mt < 4; mt++) {
            int gmt = wave * 4 + mt;
            const unsigned short* ap = Sp1c + ((size_t)(k0 * 16 + gmt) * 2) * 512 + lane * 8;
            ahb[buf][mt] = *(const bf16x8*)ap;
            alb[buf][mt] = *(const bf16x8*)(ap + 512);
        }
    };

    load_tile(0);
    loadA(0, 0);
    store_tile();
#pragma unroll
    for (int k0 = 0; k0 < 2; k0++) {
        __syncthreads();
        if (k0 + 1 < 2) { load_tile(k0 + 1); loadA(k0 + 1, 1); }
#pragma unroll
        for (int nt = 0; nt < 4; nt++) {
            int nl = nt * 16 + lr;
            bf16x8 bh, bl;
#pragma unroll
            for (int j = 0; j < 8; j++) {
                unsigned u = Bt[(quad * 8 + j) * 65 + nl];
                bh[j] = (short)(u & 0xffffu);
                bl[j] = (short)(u >> 16);
            }
#pragma unroll
            for (int mt = 0; mt < 4; mt++) {
                acc[mt][nt] = __builtin_amdgcn_mfma_f32_16x16x32_bf16(ahb[k0][mt], bh, acc[mt][nt], 0, 0, 0);
                acc[mt][nt] = __builtin_amdgcn_mfma_f32_16x16x32_bf16(ahb[k0][mt], bl, acc[mt][nt], 0, 0, 0);
                acc[mt][nt] = __builtin_amdgcn_mfma_f32_16x16x32_bf16(alb[k0][mt], bh, acc[mt][nt], 0, 0, 0);
            }
        }
        __syncthreads();
        if (k0 + 1 < 2) store_tile();
    }

#pragma unroll
    for (int nt = 0; nt < 4; nt++) {
        int b = nt * 16 + lr;
#pragma unroll
        for (int r = 0; r < 4; r++) {
            int a4 = quad * 4 + r;
            us4 w;
#pragma unroll
            for (int mt = 0; mt < 4; mt++) w[mt] = f2h_bits(acc[mt][nt][r] * scale);
            size_t addr = (size_t)cc * 16777216 +
                          (size_t)(o * 256 + m2 * 16 + a4) * 16384 +
                          (size_t)(l * 2 + (wave >> 1)) * 512 + b * 8 + (wave & 1) * 4;
            *(us4*)(t1 + addr) = w;
        }
    }
}

// ---- G2: B panel LDS-staged via global_load_lds; A depth-2 prefetch ------
// grid 2048 = cc(2) x [o(4) m2(16) a4(16)]
__global__ __launch_bounds__(256) void gemm_g2(const unsigned short* __restrict__ Bp,
                                               const unsigned short* __restrict__ Ap,
                                               unsigned short* __restrict__ Co) {
    __shared__ __align__(16) unsigned short Bs[16384];   // 32KB panel
    const int tid = threadIdx.x, lane = tid & 63, wave = tid >> 6;
    const int quad = lane >> 4, lr = lane & 15;
    const int cc = blockIdx.x >> 10, rid = blockIdx.x & 1023;
    const int o = rid >> 8, m2 = (rid >> 4) & 15, a4 = rid & 15;
    const unsigned short* pb = Bp + (size_t)blockIdx.x * 16384;
    unsigned short* Cb = Co + (size_t)cc * 16777216;

#pragma unroll
    for (int i = 0; i < 8; i++)
        gl_lds16(pb + i * 2048 + tid * 8, Bs + i * 2048 + wave * 512);

    f32x4 acc[4][4];
#pragma unroll
    for (int i = 0; i < 4; i++)
#pragma unroll
        for (int j = 0; j < 4; j++)
#pragma unroll
            for (int r = 0; r < 4; r++) acc[i][j][r] = 0.0f;

    f16x8 ah[3][4];
    auto loadA = [&](int k0, int buf) {
#pragma unroll
        for (int mt = 0; mt < 4; mt++) {
            int gmt = wave * 4 + mt;
            ah[buf][mt] = *(const f16x8*)(Ap + ((size_t)(k0 * 16 + gmt) * 2) * 512 + lane * 8);
        }
    };
    loadA(0, 0);
    loadA(1, 1);

    asm volatile("s_waitcnt vmcnt(0)" ::: "memory");
    __syncthreads();

#pragma unroll
    for (int k0 = 0; k0 < 8; k0++) {
        if (k0 + 2 < 8) loadA(k0 + 2, (k0 + 2) % 3);
        f16x8 bfr[4];
#pragma unroll
        for (int nt = 0; nt < 4; nt++)
            bfr[nt] = *(const f16x8*)(Bs + (k0 * 4 + quad) * 512 + (nt * 16 + lr) * 8);
#pragma unroll
        for (int nt = 0; nt < 4; nt++)
#pragma unroll
            for (int mt = 0; mt < 4; mt++)
                acc[mt][nt] = __builtin_amdgcn_mfma_f32_16x16x32_f16(
                    ah[k0 % 3][mt], bfr[nt], acc[mt][nt], 0, 0, 0);
    }

#pragma unroll
    for (int nt = 0; nt < 4; nt++) {
        int b = nt * 16 + lr;
#pragma unroll
        for (int r = 0; r < 4; r++) {
            int L = quad * 4 + r;
            us4 w;
#pragma unroll
            for (int mt = 0; mt < 4; mt++) w[mt] = f2h_bits(acc[mt][nt][r]);
            size_t addr = (size_t)(L * 256 + m2 * 16 + a4) * 4096 +
                          (size_t)(o * 2 + (wave >> 1)) * 512 + b * 8 + (wave & 1) * 4;
            *(us4*)(Cb + addr) = w;
        }
    }
}

// ---- fused G3+G4+G5: B panel computed in-kernel from T2 x Op3 ------------
// grid 2048 = cc(2) x rid, rid = g*32 + O2*8 + low, panel (L,a4) = g*8+low.
// (XCD-aware: the 4 O2-sharers of one T2 panel are 8 apart -> same XCD,
//  temporally adjacent -> L2 hits on the 3 re-reads.)
// Prologue: for m2=0..15: acc3 = Op3[mt=O2] x T2[(L,m2,a4)] (2 MFMAs, T2
//   depth-2 ring prefetch), f2h -> Bs at g3's exact byte layout.
// Writes split-u32 env (envSo) always; fp32 env only when wf32 (q==6).
__global__ __launch_bounds__(256) void gemm_g45(const unsigned short* __restrict__ T2,
                                                const unsigned short* __restrict__ Op3q,
                                                const unsigned short* __restrict__ Ap4,
                                                const unsigned short* __restrict__ Sp5,
                                                float* __restrict__ env,
                                                unsigned* __restrict__ envSo,
                                                int A0, float inv, int wf32) {
    __shared__ __align__(16) unsigned short Bs[16384];   // 32KB B panel
    __shared__ unsigned SL[4 * 16 * 68];                 // slab / reduce buffer
    const int tid = threadIdx.x, lane = tid & 63, wave = tid >> 6;
    const int quad = lane >> 4, lr = lane & 15;
    const int cc = blockIdx.x >> 10, rid = blockIdx.x & 1023;
    const int low = rid & 7, O2 = (rid >> 3) & 3, g = rid >> 5;
    const int panel = g * 8 + low;           // = L*16 + a4
    const int L = panel >> 4, a4 = panel & 15;
    const unsigned short* T2c = T2 + (size_t)cc * 16777216;
    const int b8 = (wave * 16 + lr) * 8;   // b*8, b = wave*16+lr (g3 layout)

    // phase-A A-panel prefetch rides alongside the prologue
    f16x8 ah[3][4];
    auto loadA = [&](int k0, int buf) {
#pragma unroll
        for (int mt = 0; mt < 4; mt++) {
            int gmt = wave * 4 + mt;
            ah[buf][mt] = *(const f16x8*)(Ap4 + ((size_t)(k0 * 16 + gmt) * 2) * 512 + lane * 8);
        }
    };
    loadA(0, 0);
    loadA(1, 1);

    // ---- fused G3 prologue: build Bs = Op3[O2] x T2[(L,m2,a4)] -----------
    {
        f16x8 oh0 = *(const f16x8*)(Op3q + (size_t)(O2 * 2) * 512 + lane * 8);
        f16x8 oh1 = *(const f16x8*)(Op3q + (size_t)((4 + O2) * 2) * 512 + lane * 8);
        f16x8 tb[3][2];
        auto loadT2 = [&](int m2, int buf) {
            const unsigned short* pp = T2c + (size_t)(L * 256 + m2 * 16 + a4) * 4096;
            tb[buf][0] = *(const f16x8*)(pp + (quad << 9) + b8);
            tb[buf][1] = *(const f16x8*)(pp + ((4 + quad) << 9) + b8);
        };
        loadT2(0, 0);
        loadT2(1, 1);
#pragma unroll
        for (int m2 = 0; m2 < 16; m2++) {
            if (m2 + 2 < 16) loadT2(m2 + 2, (m2 + 2) % 3);
            f32x4 a3;
            a3[0] = a3[1] = a3[2] = a3[3] = 0.0f;
            a3 = __builtin_amdgcn_mfma_f32_16x16x32_f16(oh0, tb[m2 % 3][0], a3, 0, 0, 0);
            a3 = __builtin_amdgcn_mfma_f32_16x16x32_f16(oh1, tb[m2 % 3][1], a3, 0, 0, 0);
            us4 w;
#pragma unroll
            for (int r = 0; r < 4; r++) w[r] = f2h_bits(a3[r]);
            *(us4*)(Bs + (m2 * 2 + (quad >> 1)) * 512 + b8 + (quad & 1) * 4) = w;
        }
    }
    __syncthreads();

    f32x4 acc[4][4];
#pragma unroll
    for (int i = 0; i < 4; i++)
#pragma unroll
        for (int j = 0; j < 4; j++)
#pragma unroll
            for (int r = 0; r < 4; r++) acc[i][j][r] = 0.0f;

#pragma unroll
    for (int k0 = 0; k0 < 8; k0++) {
        if (k0 + 2 < 8) loadA(k0 + 2, (k0 + 2) % 3);
        f16x8 bfr[4];
#pragma unroll
        for (int nt = 0; nt < 4; nt++)
            bfr[nt] = *(const f16x8*)(Bs + (k0 * 4 + quad) * 512 + (nt * 16 + lr) * 8);
#pragma unroll
        for (int nt = 0; nt < 4; nt++)
#pragma unroll
            for (int mt = 0; mt < 4; mt++)
                acc[mt][nt] = __builtin_amdgcn_mfma_f32_16x16x32_f16(
                    ah[k0 % 3][mt], bfr[nt], acc[mt][nt], 0, 0, 0);
    }

    // phase B: per-wave k-quarter (s = 4*wave..4*wave+3), barrier-free.
    unsigned* myslab = SL + wave * (16 * 68);
    f32x4 acc5[4];
#pragma unroll
    for (int nt = 0; nt < 4; nt++)
#pragma unroll
        for (int r = 0; r < 4; r++) acc5[nt][r] = 0.0f;

    // Sp5 depth-1 pipeline: step = mtp*2+h, buffers by step parity.
    bf16x8 s5h[2][4], s5l[2][4];
    auto loadS5 = [&](int step, int buf) {
        int kg = (wave * 4 + (step >> 1)) * 2 + (step & 1);
#pragma unroll
        for (int nt = 0; nt < 4; nt++) {
            const unsigned short* bp = Sp5 + ((size_t)(kg * 4 + nt) * 2) * 512 + lane * 8;
            s5h[buf][nt] = *(const bf16x8*)bp;
            s5l[buf][nt] = *(const bf16x8*)(bp + 512);
        }
    };
    loadS5(0, 0);

#pragma unroll
    for (int mtp = 0; mtp < 4; mtp++) {
        // deposit own slab [M2=16][b=64 pad 68] (u32 split-pair)
#pragma unroll
        for (int nt = 0; nt < 4; nt++)
#pragma unroll
            for (int r = 0; r < 4; r++)
                myslab[(quad * 4 + r) * 68 + nt * 16 + lr] = split2(acc[mtp][nt][r]);
        // same-wave cross-lane LDS dependency: drain LDS pipe (vmcnt loads
        // from loadS5 stay in flight - lgkmcnt does not wait on them)
        asm volatile("s_waitcnt lgkmcnt(0)" ::: "memory");
#pragma unroll
        for (int h = 0; h < 2; h++) {
            const int step = mtp * 2 + h;
            const unsigned* sp = &myslab[lr * 68 + h * 32 + quad * 8];
            uint4 u0 = *(const uint4*)sp;
            uint4 u1 = *(const uint4*)(sp + 4);
            bf16x8 th, tl;
            th[0] = (short)(u0.x & 0xffff); tl[0] = (short)(u0.x >> 16);
            th[1] = (short)(u0.y & 0xffff); tl[1] = (short)(u0.y >> 16);
            th[2] = (short)(u0.z & 0xffff); tl[2] = (short)(u0.z >> 16);
            th[3] = (short)(u0.w & 0xffff); tl[3] = (short)(u0.w >> 16);
            th[4] = (short)(u1.x & 0xffff); tl[4] = (short)(u1.x >> 16);
            th[5] = (short)(u1.y & 0xffff); tl[5] = (short)(u1.y >> 16);
            th[6] = (short)(u1.z & 0xffff); tl[6] = (short)(u1.z >> 16);
            th[7] = (short)(u1.w & 0xffff); tl[7] = (short)(u1.w >> 16);
            if (step + 1 < 8) loadS5(step + 1, (step + 1) & 1);
#pragma unroll
            for (int nt = 0; nt < 4; nt++) {
                acc5[nt] = __builtin_amdgcn_mfma_f32_16x16x32_bf16(th, s5h[step & 1][nt], acc5[nt], 0, 0, 0);
                acc5[nt] = __builtin_amdgcn_mfma_f32_16x16x32_bf16(th, s5l[step & 1][nt], acc5[nt], 0, 0, 0);
                acc5[nt] = __builtin_amdgcn_mfma_f32_16x16x32_bf16(tl, s5h[step & 1][nt], acc5[nt], 0, 0, 0);
            }
        }
    }

    // cross-wave reduce: one barrier, float view of SL
    __syncthreads();
    float* red = (float*)SL;
#pragma unroll
    for (int nt = 0; nt < 4; nt++)
#pragma unroll
        for (int r = 0; r < 4; r++)
            red[wave * 1088 + (quad * 4 + r) * 68 + nt * 16 + lr] = acc5[nt][r];
    __syncthreads();
#pragma unroll
    for (int r = 0; r < 4; r++) {
        int M2 = quad * 4 + r, Bc = wave * 16 + lr;
        float v = red[M2 * 68 + Bc] + red[1088 + M2 * 68 + Bc] +
                  red[2176 + M2 * 68 + Bc] + red[3264 + M2 * 68 + Bc];
        float w = v * inv;
        size_t idx = (size_t)(L * 64 + O2 * 16 + M2) * 4096 + (A0 + cc * 16 + a4) * 64 + Bc;
        envSo[idx] = split2(w);
        if (wf32) env[idx] = w;
    }
}

extern "C" void kernel_launch(void* const* d_in, const int* in_sizes, int n_in,
                              void* d_out, int out_size, void* d_ws, size_t ws_size,
                              hipStream_t stream) {
    const float* state = (const float*)d_in[0];   // [8,64,16,64]
    const float* layer = (const float*)d_in[1];   // [1,8,16,16,16,16]
    const float* oper  = (const float*)d_in[2];   // [8,4,16,16,4]
    float* out = (float*)d_out;

    // F 64MiB | P 128MiB | envS0 16MiB | envB 16MiB | envS1 16MiB | packs | sv
    const size_t need = 16777216ull * 4 + 33554432ull * 4 + 3ull * 4194304ull * 4 +
                        (4ull * 1048576ull + 65536ull) * 2ull + 4096ull;
    if (ws_size < need) {
        write_diag_kernel<<<1, 64, 0, stream>>>(out, (float)ws_size);
        return;
    }
    float* F    = (float*)d_ws;                          // SCR fp32 / T2 u16
    unsigned* P = (unsigned*)(F + 16777216);             // T1 (u16)
    unsigned* envS0 = (unsigned*)(P + 33554432);
    float* envB = (float*)(envS0 + 4194304);
    unsigned* envS1 = (unsigned*)(envB + 4194304);
    unsigned short* Ap2 = (unsigned short*)(envS1 + 4194304);
    unsigned short* Ap4 = Ap2 + 1048576;
    unsigned short* Sp1 = Ap4 + 1048576;
    unsigned short* Sp5 = Sp1 + 1048576;
    unsigned short* Op3 = Sp5 + 1048576;
    float* sv = (float*)(Op3 + 65536);
    float* SCR = F;
    unsigned short* T1 = (unsigned short*)P;
    unsigned short* T2 = (unsigned short*)F;

    prep_apack<<<256, 256, 0, stream>>>(layer, Ap2, Ap4);
    prep_spack1<<<256, 256, 0, stream>>>(state, Sp1);
    prep_spack5<<<256, 256, 0, stream>>>(state, Sp5);
    prep_opack3<<<16, 256, 0, stream>>>(oper, Op3);
    prep_sv<<<4, 256, 0, stream>>>(state, sv);

    // site 0 -> envB (exact fp32), then one split into envS1
    s0_g2<<<64, 256, 0, stream>>>(state, layer, SCR);
    s0_g3<<<256, 256, 0, stream>>>(SCR, oper, SCR + 16384);
    s0_g4<<<4096, 256, 0, stream>>>(SCR + 16384, layer, SCR + 81920);
    s0_env<<<16384, 256, 0, stream>>>(SCR + 81920, state, envB);
    env_split_k<<<4096, 256, 0, stream>>>(envB, envS1);

    for (int q = 1; q < 7; q++) {
        unsigned* einS  = (q & 1) ? envS1 : envS0;
        unsigned* eoutS = (q & 1) ? envS0 : envS1;
        float scl = (float)(1u << (16 + 2 * q));   // exact power of 2
        float inv = 1.0f / scl;
        int wf32 = (q == 6) ? 1 : 0;
        for (int p = 0; p < 2; p++) {
            gemm_g1<<<2048, 256, 0, stream>>>(
                einS, Sp1 + (size_t)(q * 4 + p * 2) * 32768, T1, scl);
            gemm_g2<<<2048, 256, 0, stream>>>(
                T1, Ap2 + (size_t)q * 131072, T2);
            gemm_g45<<<2048, 256, 0, stream>>>(
                T2, Op3 + (size_t)q * 8192, Ap4 + (size_t)q * 131072,
                Sp5 + (size_t)q * 131072, envB, eoutS, p * 32, inv, wf32);
        }
    }

    // site 7: out = <env7 (in envB), w>
    s7_c1<<<64, 256, 0, stream>>>(state, layer, SCR);
    s7_c2<<<256, 256, 0, stream>>>(SCR, oper, SCR + 16384);
    s7_c3<<<4096, 256, 0, stream>>>(SCR + 16384, layer, SCR + 81920);
    zero_out<<<1, 64, 0, stream>>>(out);
    s7_fused<<<1024, 256, 0, stream>>>(envB, SCR + 81920, sv, out);
}